// Round 1
// baseline (3596.212 us; speedup 1.0000x reference)
//
#include <hip/hip_runtime.h>
#include <cstdint>
#include <cstddef>

#define B_ 2
#define N_ 2048
#define C_ 384
#define K_ 20
#define EPS_ 1e-5f
#define SLOPE_ 0.2f

// ---------------- monotonic float<->uint mapping for atomicMax ----------------
__device__ __forceinline__ unsigned fmap(float f) {
  unsigned u = __float_as_uint(f);
  return (u & 0x80000000u) ? ~u : (u | 0x80000000u);
}
__device__ __forceinline__ float funmap(unsigned u) {
  unsigned bits = (u & 0x80000000u) ? (u ^ 0x80000000u) : ~u;
  return __uint_as_float(bits);
}

// ---------------- transpose x (B,C,N) -> xb (B,N,C) ----------------
__global__ __launch_bounds__(256) void k_transpose(const float* __restrict__ x,
                                                   float* __restrict__ xb) {
  __shared__ float tile[32][33];
  int bn = blockIdx.x;   // N/32
  int bc = blockIdx.y;   // C/32
  int b  = blockIdx.z;
  int tx = threadIdx.x & 31, ty = threadIdx.x >> 5;  // 32 x 8
  const float* src = x + ((size_t)b * C_ + bc * 32) * N_ + bn * 32;
#pragma unroll
  for (int j = 0; j < 32; j += 8)
    tile[ty + j][tx] = src[(size_t)(ty + j) * N_ + tx];
  __syncthreads();
  float* dst = xb + ((size_t)b * N_ + bn * 32) * C_ + bc * 32;
#pragma unroll
  for (int j = 0; j < 32; j += 8)
    dst[(size_t)(ty + j) * C_ + tx] = tile[tx][ty + j];
}

// ---------------- row squared norms ----------------
__global__ __launch_bounds__(256) void k_rowsq(const float* __restrict__ xin, int ldx,
                                               float* __restrict__ sq) {
  int row  = blockIdx.x * 4 + (threadIdx.x >> 6);  // b*N+n
  int lane = threadIdx.x & 63;
  const float* p = xin + (size_t)row * ldx;
  float v = 0.f;
#pragma unroll
  for (int i = 0; i < C_ / 64; i++) {
    float t = p[lane + i * 64];
    v += t * t;
  }
#pragma unroll
  for (int off = 32; off; off >>= 1) v += __shfl_xor(v, off, 64);
  if (lane == 0) sq[row] = v;
}

// ---------------- Gram matrix G[b][i][j] = x_i . x_j (64x64 tiles) ----------------
__global__ __launch_bounds__(256) void k_gram(const float* __restrict__ xin, int ldx,
                                              float* __restrict__ G) {
  __shared__ __align__(16) float As[16][64];
  __shared__ __align__(16) float Bs[16][64];
  int bi = blockIdx.x, bj = blockIdx.y, b = blockIdx.z;
  int t  = threadIdx.x;
  int tx = t & 15, ty = t >> 4;
  int lr = t >> 2, lc4 = t & 3;  // loader: row 0..63, c sub-chunk
  const float* base = xin + (size_t)b * N_ * ldx;
  float acc[4][4] = {};

  for (int kc = 0; kc < C_; kc += 16) {
    float4 av = *(const float4*)(base + (size_t)(bi * 64 + lr) * ldx + kc + lc4 * 4);
    float4 bv = *(const float4*)(base + (size_t)(bj * 64 + lr) * ldx + kc + lc4 * 4);
    __syncthreads();
    As[lc4 * 4 + 0][lr] = av.x; As[lc4 * 4 + 1][lr] = av.y;
    As[lc4 * 4 + 2][lr] = av.z; As[lc4 * 4 + 3][lr] = av.w;
    Bs[lc4 * 4 + 0][lr] = bv.x; Bs[lc4 * 4 + 1][lr] = bv.y;
    Bs[lc4 * 4 + 2][lr] = bv.z; Bs[lc4 * 4 + 3][lr] = bv.w;
    __syncthreads();
#pragma unroll
    for (int kk = 0; kk < 16; kk++) {
      float4 a = *(const float4*)&As[kk][ty * 4];
      float4 q = *(const float4*)&Bs[kk][tx * 4];
      float aa[4] = {a.x, a.y, a.z, a.w};
      float qq[4] = {q.x, q.y, q.z, q.w};
#pragma unroll
      for (int i = 0; i < 4; i++)
#pragma unroll
        for (int j = 0; j < 4; j++) acc[i][j] += aa[i] * qq[j];
    }
  }
  float* gout = G + ((size_t)b * N_ + bi * 64 + ty * 4) * N_ + bj * 64 + tx * 4;
#pragma unroll
  for (int i = 0; i < 4; i++) {
    float4 w = make_float4(acc[i][0], acc[i][1], acc[i][2], acc[i][3]);
    *(float4*)(gout + (size_t)i * N_) = w;
  }
}

// ---------------- top-K (K=20) per row of neg_dist ----------------
__global__ __launch_bounds__(256) void k_topk(const float* __restrict__ G,
                                              const float* __restrict__ sq,
                                              int* __restrict__ idx) {
  __shared__ float vals[N_];
  __shared__ float wbv[4];
  __shared__ int wbi[4];
  int n = blockIdx.x, b = blockIdx.y, t = threadIdx.x;
  const float* grow = G + ((size_t)b * N_ + n) * N_;
  const float* sqb  = sq + (size_t)b * N_;
  float sqn = sqb[n];
#pragma unroll
  for (int i = 0; i < N_ / 256; i++) {
    int j = t + i * 256;
    vals[j] = 2.f * grow[j] - sqn - sqb[j];
  }
  __syncthreads();
  int* orow = idx + ((size_t)b * N_ + n) * K_;
  for (int it = 0; it < K_; it++) {
    float bv = -INFINITY;
    int  bi = 1 << 30;
#pragma unroll
    for (int i = 0; i < N_ / 256; i++) {
      int j  = t + i * 256;
      float v = vals[j];
      if (v > bv || (v == bv && j < bi)) { bv = v; bi = j; }
    }
#pragma unroll
    for (int off = 32; off; off >>= 1) {
      float v2 = __shfl_xor(bv, off, 64);
      int   i2 = __shfl_xor(bi, off, 64);
      if (v2 > bv || (v2 == bv && i2 < bi)) { bv = v2; bi = i2; }
    }
    int w = t >> 6;
    if ((t & 63) == 0) { wbv[w] = bv; wbi[w] = bi; }
    __syncthreads();
    if (t == 0) {
#pragma unroll
      for (int ww = 1; ww < 4; ww++)
        if (wbv[ww] > bv || (wbv[ww] == bv && wbi[ww] < bi)) { bv = wbv[ww]; bi = wbi[ww]; }
      orow[it] = bi;
      vals[bi] = -INFINITY;
    }
    __syncthreads();
  }
}

// ---------------- weight prep: W (384,768) -> W1q/Wdq [c4][o] float4 ----------------
__global__ void k_prepw(const float* __restrict__ We, float4* __restrict__ W1q,
                        float4* __restrict__ Wdq) {
  int t = blockIdx.x * 256 + threadIdx.x;
  if (t >= (C_ / 4) * C_) return;
  int o = t % C_, c4 = t / C_;
  float4 w1 = *(const float4*)(We + (size_t)o * 2 * C_ + c4 * 4);
  float4 w2 = *(const float4*)(We + (size_t)o * 2 * C_ + C_ + c4 * 4);
  W1q[t] = w1;
  Wdq[t] = make_float4(w2.x - w1.x, w2.y - w1.y, w2.z - w1.z, w2.w - w1.w);
}

__global__ void k_prepwp(const float* __restrict__ Wp, float4* __restrict__ Wpq) {
  int t = blockIdx.x * 256 + threadIdx.x;
  if (t >= (3 * C_ / 4) * C_) return;
  int o = t % C_, c4 = t / C_;
  Wpq[t] = *(const float4*)(Wp + (size_t)o * 3 * C_ + c4 * 4);
}

// ---------------- fused edge conv + BN + leaky + max over K ----------------
__global__ __launch_bounds__(384) void k_edgeconv(
    const float* __restrict__ xin, int ldx, const int* __restrict__ idx,
    const float4* __restrict__ W1q, const float4* __restrict__ Wdq,
    const float* __restrict__ g, const float* __restrict__ bb,
    const float* __restrict__ m, const float* __restrict__ v,
    float* __restrict__ xout, int ldo) {
  int n = blockIdx.x, b = blockIdx.y, o = threadIdx.x;
  __shared__ int sidx[K_];
  if (o < K_) sidx[o] = idx[((size_t)b * N_ + n) * K_ + o];
  __syncthreads();
  const float* base = xin + (size_t)b * N_ * ldx;
  const float4* nb[K_];
#pragma unroll
  for (int k = 0; k < K_; k++) {
    int j = __builtin_amdgcn_readfirstlane(sidx[k]);
    nb[k] = (const float4*)(base + (size_t)j * ldx);
  }
  const float4* xc = (const float4*)(base + (size_t)n * ldx);
  float acc[K_] = {};
  float accc = 0.f;
  for (int c4 = 0; c4 < C_ / 4; c4++) {
    float4 w1  = W1q[c4 * C_ + o];
    float4 wd  = Wdq[c4 * C_ + o];
    float4 xcv = xc[c4];
    accc += xcv.x * wd.x + xcv.y * wd.y + xcv.z * wd.z + xcv.w * wd.w;
#pragma unroll
    for (int k = 0; k < K_; k++) {
      float4 nv = nb[k][c4];
      acc[k] += nv.x * w1.x + nv.y * w1.y + nv.z * w1.z + nv.w * w1.w;
    }
  }
  float sc = g[o] * rsqrtf(v[o] + EPS_);
  float bi_ = bb[o] - m[o] * sc;
  float hmax = -INFINITY;
#pragma unroll
  for (int k = 0; k < K_; k++) {
    float h = acc[k] + accc;
    float y = h * sc + bi_;
    y = y > 0.f ? y : SLOPE_ * y;
    hmax = fmaxf(hmax, y);
  }
  xout[((size_t)b * N_ + n) * ldo + o] = hmax;
}

// ---------------- final projection + BN + leaky + max over N ----------------
__global__ __launch_bounds__(384) void k_final(const float* __restrict__ cat,
                                               const float4* __restrict__ Wpq,
                                               const float* __restrict__ gp,
                                               const float* __restrict__ bp,
                                               const float* __restrict__ mp,
                                               const float* __restrict__ vp,
                                               unsigned* __restrict__ stage) {
  int nc = blockIdx.x, b = blockIdx.y, o = threadIdx.x;
  float sc = gp[o] * rsqrtf(vp[o] + EPS_);
  float bi_ = bp[o] - mp[o] * sc;
  float vmax = -INFINITY;
  for (int nn = 0; nn < 16; nn++) {
    const float4* row = (const float4*)(cat + ((size_t)b * N_ + nc * 16 + nn) * (3 * C_));
    float acc = 0.f;
    for (int c4 = 0; c4 < 3 * C_ / 4; c4++) {
      float4 xcv = row[c4];
      float4 w   = Wpq[c4 * C_ + o];
      acc += xcv.x * w.x + xcv.y * w.y + xcv.z * w.z + xcv.w * w.w;
    }
    float y = acc * sc + bi_;
    y = y > 0.f ? y : SLOPE_ * y;
    vmax = fmaxf(vmax, y);
  }
  atomicMax(stage + (size_t)b * C_ + o, fmap(vmax));
}

__global__ void k_init(unsigned* __restrict__ stage) {
  int t = blockIdx.x * 256 + threadIdx.x;
  if (t < B_ * C_) stage[t] = 0x007FFFFFu;  // fmap(-inf)
}

__global__ void k_unmap(const unsigned* __restrict__ stage, float* __restrict__ out) {
  int t = blockIdx.x * 256 + threadIdx.x;
  if (t < B_ * C_) out[t] = funmap(stage[t]);
}

// ---------------- host ----------------
extern "C" void kernel_launch(void* const* d_in, const int* in_sizes, int n_in,
                              void* d_out, int out_size, void* d_ws, size_t ws_size,
                              hipStream_t stream) {
  const float* x   = (const float*)d_in[0];
  const float* We[3] = {(const float*)d_in[2], (const float*)d_in[7], (const float*)d_in[12]};
  const float* g[3]  = {(const float*)d_in[3], (const float*)d_in[8], (const float*)d_in[13]};
  const float* bb[3] = {(const float*)d_in[4], (const float*)d_in[9], (const float*)d_in[14]};
  const float* m[3]  = {(const float*)d_in[5], (const float*)d_in[10], (const float*)d_in[15]};
  const float* v[3]  = {(const float*)d_in[6], (const float*)d_in[11], (const float*)d_in[16]};
  const float* Wp = (const float*)d_in[17];
  const float* gp = (const float*)d_in[18];
  const float* bp = (const float*)d_in[19];
  const float* mp = (const float*)d_in[20];
  const float* vp = (const float*)d_in[21];
  float* out = (float*)d_out;

  // workspace layout (floats)
  float* ws   = (float*)d_ws;
  float* xb   = ws;                                   // B*N*C
  float* xcat = xb + (size_t)B_ * N_ * C_;            // B*N*3C
  float* G    = xcat + (size_t)B_ * N_ * 3 * C_;      // B*N*N
  float* sq   = G + (size_t)B_ * N_ * N_;             // B*N
  int*   idx  = (int*)(sq + (size_t)B_ * N_);         // B*N*K
  float4* W1q = (float4*)(idx + (size_t)B_ * N_ * K_);
  float4* Wdq = W1q + 3 * (size_t)(C_ / 4) * C_;
  float4* Wpq = Wdq + 3 * (size_t)(C_ / 4) * C_;
  unsigned* stage = (unsigned*)(Wpq + (size_t)(3 * C_ / 4) * C_);

  // weight prep
  for (int l = 0; l < 3; l++)
    k_prepw<<<dim3(((C_ / 4) * C_ + 255) / 256), 256, 0, stream>>>(
        We[l], W1q + (size_t)l * (C_ / 4) * C_, Wdq + (size_t)l * (C_ / 4) * C_);
  k_prepwp<<<dim3(((3 * C_ / 4) * C_ + 255) / 256), 256, 0, stream>>>(Wp, Wpq);

  // transpose input
  k_transpose<<<dim3(N_ / 32, C_ / 32, B_), 256, 0, stream>>>(x, xb);
  k_init<<<dim3((B_ * C_ + 255) / 256), 256, 0, stream>>>(stage);

  // three edge-conv layers
  for (int l = 0; l < 3; l++) {
    const float* xin;
    int ldx;
    if (l == 0) { xin = xb; ldx = C_; }
    else        { xin = xcat + (size_t)(l - 1) * C_; ldx = 3 * C_; }
    float* xout = xcat + (size_t)l * C_;

    k_rowsq<<<dim3(B_ * N_ / 4), 256, 0, stream>>>(xin, ldx, sq);
    k_gram<<<dim3(N_ / 64, N_ / 64, B_), 256, 0, stream>>>(xin, ldx, G);
    k_topk<<<dim3(N_, B_), 256, 0, stream>>>(G, sq, idx);
    k_edgeconv<<<dim3(N_, B_), 384, 0, stream>>>(
        xin, ldx, idx, W1q + (size_t)l * (C_ / 4) * C_, Wdq + (size_t)l * (C_ / 4) * C_,
        g[l], bb[l], m[l], v[l], xout, 3 * C_);
  }

  // final projection + global max
  k_final<<<dim3(N_ / 16, B_), 384, 0, stream>>>(xcat, Wpq, gp, bp, mp, vp, stage);
  k_unmap<<<dim3((B_ * C_ + 255) / 256), 256, 0, stream>>>(stage, out);
}

// Round 2
// 991.308 us; speedup vs baseline: 3.6277x; 3.6277x over previous
//
#include <hip/hip_runtime.h>
#include <cstdint>
#include <cstddef>

#define B_ 2
#define N_ 2048
#define C_ 384
#define K_ 20
#define EPS_ 1e-5f
#define SLOPE_ 0.2f

// ---------------- monotonic float<->uint mapping for atomicMax ----------------
__device__ __forceinline__ unsigned fmap(float f) {
  unsigned u = __float_as_uint(f);
  return (u & 0x80000000u) ? ~u : (u | 0x80000000u);
}
__device__ __forceinline__ float funmap(unsigned u) {
  unsigned bits = (u & 0x80000000u) ? (u ^ 0x80000000u) : ~u;
  return __uint_as_float(bits);
}

// ---------------- transpose x (B,C,N) -> xb (B,N,C) ----------------
__global__ __launch_bounds__(256) void k_transpose(const float* __restrict__ x,
                                                   float* __restrict__ xb) {
  __shared__ float tile[32][33];
  int bn = blockIdx.x;   // N/32
  int bc = blockIdx.y;   // C/32
  int b  = blockIdx.z;
  int tx = threadIdx.x & 31, ty = threadIdx.x >> 5;  // 32 x 8
  const float* src = x + ((size_t)b * C_ + bc * 32) * N_ + bn * 32;
#pragma unroll
  for (int j = 0; j < 32; j += 8)
    tile[ty + j][tx] = src[(size_t)(ty + j) * N_ + tx];
  __syncthreads();
  float* dst = xb + ((size_t)b * N_ + bn * 32) * C_ + bc * 32;
#pragma unroll
  for (int j = 0; j < 32; j += 8)
    dst[(size_t)(ty + j) * C_ + tx] = tile[tx][ty + j];
}

// ---------------- row squared norms ----------------
__global__ __launch_bounds__(256) void k_rowsq(const float* __restrict__ xin, int ldx,
                                               float* __restrict__ sq) {
  int row  = blockIdx.x * 4 + (threadIdx.x >> 6);  // b*N+n
  int lane = threadIdx.x & 63;
  const float* p = xin + (size_t)row * ldx;
  float v = 0.f;
#pragma unroll
  for (int i = 0; i < C_ / 64; i++) {
    float t = p[lane + i * 64];
    v += t * t;
  }
#pragma unroll
  for (int off = 32; off; off >>= 1) v += __shfl_xor(v, off, 64);
  if (lane == 0) sq[row] = v;
}

// ---------------- Gram matrix G[b][i][j] = x_i . x_j (64x64 tiles) ----------------
__global__ __launch_bounds__(256) void k_gram(const float* __restrict__ xin, int ldx,
                                              float* __restrict__ G) {
  __shared__ __align__(16) float As[16][64];
  __shared__ __align__(16) float Bs[16][64];
  int bi = blockIdx.x, bj = blockIdx.y, b = blockIdx.z;
  int t  = threadIdx.x;
  int tx = t & 15, ty = t >> 4;
  int lr = t >> 2, lc4 = t & 3;  // loader: row 0..63, c sub-chunk
  const float* base = xin + (size_t)b * N_ * ldx;
  float acc[4][4] = {};

  for (int kc = 0; kc < C_; kc += 16) {
    float4 av = *(const float4*)(base + (size_t)(bi * 64 + lr) * ldx + kc + lc4 * 4);
    float4 bv = *(const float4*)(base + (size_t)(bj * 64 + lr) * ldx + kc + lc4 * 4);
    __syncthreads();
    As[lc4 * 4 + 0][lr] = av.x; As[lc4 * 4 + 1][lr] = av.y;
    As[lc4 * 4 + 2][lr] = av.z; As[lc4 * 4 + 3][lr] = av.w;
    Bs[lc4 * 4 + 0][lr] = bv.x; Bs[lc4 * 4 + 1][lr] = bv.y;
    Bs[lc4 * 4 + 2][lr] = bv.z; Bs[lc4 * 4 + 3][lr] = bv.w;
    __syncthreads();
#pragma unroll
    for (int kk = 0; kk < 16; kk++) {
      float4 a = *(const float4*)&As[kk][ty * 4];
      float4 q = *(const float4*)&Bs[kk][tx * 4];
      float aa[4] = {a.x, a.y, a.z, a.w};
      float qq[4] = {q.x, q.y, q.z, q.w};
#pragma unroll
      for (int i = 0; i < 4; i++)
#pragma unroll
        for (int j = 0; j < 4; j++) acc[i][j] += aa[i] * qq[j];
    }
  }
  float* gout = G + ((size_t)b * N_ + bi * 64 + ty * 4) * N_ + bj * 64 + tx * 4;
#pragma unroll
  for (int i = 0; i < 4; i++) {
    float4 w = make_float4(acc[i][0], acc[i][1], acc[i][2], acc[i][3]);
    *(float4*)(gout + (size_t)i * N_) = w;
  }
}

// ---------------- top-K (K=20) per row of neg_dist ----------------
__global__ __launch_bounds__(256) void k_topk(const float* __restrict__ G,
                                              const float* __restrict__ sq,
                                              int* __restrict__ idx) {
  __shared__ float vals[N_];
  __shared__ float wbv[4];
  __shared__ int wbi[4];
  int n = blockIdx.x, b = blockIdx.y, t = threadIdx.x;
  const float* grow = G + ((size_t)b * N_ + n) * N_;
  const float* sqb  = sq + (size_t)b * N_;
  float sqn = sqb[n];
#pragma unroll
  for (int i = 0; i < N_ / 256; i++) {
    int j = t + i * 256;
    vals[j] = 2.f * grow[j] - sqn - sqb[j];
  }
  __syncthreads();
  int* orow = idx + ((size_t)b * N_ + n) * K_;
  for (int it = 0; it < K_; it++) {
    float bv = -INFINITY;
    int  bi = 1 << 30;
#pragma unroll
    for (int i = 0; i < N_ / 256; i++) {
      int j  = t + i * 256;
      float v = vals[j];
      if (v > bv || (v == bv && j < bi)) { bv = v; bi = j; }
    }
#pragma unroll
    for (int off = 32; off; off >>= 1) {
      float v2 = __shfl_xor(bv, off, 64);
      int   i2 = __shfl_xor(bi, off, 64);
      if (v2 > bv || (v2 == bv && i2 < bi)) { bv = v2; bi = i2; }
    }
    int w = t >> 6;
    if ((t & 63) == 0) { wbv[w] = bv; wbi[w] = bi; }
    __syncthreads();
    if (t == 0) {
#pragma unroll
      for (int ww = 1; ww < 4; ww++)
        if (wbv[ww] > bv || (wbv[ww] == bv && wbi[ww] < bi)) { bv = wbv[ww]; bi = wbi[ww]; }
      orow[it] = bi;
      vals[bi] = -INFINITY;
    }
    __syncthreads();
  }
}

// ---- weight prep: build Wt[c][o2] (384 x 768), scale+bias folded ----
// o2 <  384 : Wt = sc[o2]   * W_a[o2][c]
// o2 >= 384 : Wt = sc[o2-384]*(W_b - W_a)[o2-384][c],   bz[o2] = bias
__global__ void k_prepw2(const float* __restrict__ We, const float* __restrict__ g,
                         const float* __restrict__ bb, const float* __restrict__ m,
                         const float* __restrict__ v, float* __restrict__ Wt,
                         float* __restrict__ bz) {
  int t = blockIdx.x * 256 + threadIdx.x;
  if (t >= C_ * 2 * C_) return;
  int c = t / (2 * C_), o2 = t % (2 * C_);
  int o = (o2 < C_) ? o2 : (o2 - C_);
  float sc = g[o] * rsqrtf(v[o] + EPS_);
  float w;
  if (o2 < C_) w = sc * We[(size_t)o * 2 * C_ + c];
  else         w = sc * (We[(size_t)o * 2 * C_ + C_ + c] - We[(size_t)o * 2 * C_ + c]);
  Wt[t] = w;
  if (t < 2 * C_) {
    int oo = (t < C_) ? -1 : t - C_;
    bz[t] = (oo < 0) ? 0.f : (bb[oo] - m[oo] * (g[oo] * rsqrtf(v[oo] + EPS_)));
  }
}

__global__ void k_prepwp(const float* __restrict__ Wp, float4* __restrict__ Wpq) {
  int t = blockIdx.x * 256 + threadIdx.x;
  if (t >= (3 * C_ / 4) * C_) return;
  int o = t % C_, c4 = t / C_;
  Wpq[t] = *(const float4*)(Wp + (size_t)o * 3 * C_ + c4 * 4);
}

// ---- YZ GEMM: YZ[b][n][o2] = sum_c X[n][c]*Wt[c][o2] + bz[o2] ----
__global__ __launch_bounds__(256) void k_yzgemm(const float* __restrict__ xin, int ldx,
                                                const float* __restrict__ Wt,
                                                const float* __restrict__ bz,
                                                float* __restrict__ YZ) {
  __shared__ __align__(16) float As[16][64];
  __shared__ __align__(16) float Bs[16][64];
  int bi = blockIdx.x, bj = blockIdx.y, b = blockIdx.z;
  int t  = threadIdx.x;
  int tx = t & 15, ty = t >> 4;
  int lrA = t >> 2, lc4A = t & 3;   // A loader: row 0..63, c chunk 0..3
  int lrB = t >> 4, lc4B = t & 15;  // B loader: c row 0..15, col chunk 0..15
  const float* baseX = xin + (size_t)b * N_ * ldx;
  float acc[4][4] = {};

  for (int kc = 0; kc < C_; kc += 16) {
    float4 av = *(const float4*)(baseX + (size_t)(bi * 64 + lrA) * ldx + kc + lc4A * 4);
    float4 bv = *(const float4*)(Wt + (size_t)(kc + lrB) * (2 * C_) + bj * 64 + lc4B * 4);
    __syncthreads();
    As[lc4A * 4 + 0][lrA] = av.x; As[lc4A * 4 + 1][lrA] = av.y;
    As[lc4A * 4 + 2][lrA] = av.z; As[lc4A * 4 + 3][lrA] = av.w;
    *(float4*)&Bs[lrB][lc4B * 4] = bv;
    __syncthreads();
#pragma unroll
    for (int kk = 0; kk < 16; kk++) {
      float4 a = *(const float4*)&As[kk][ty * 4];
      float4 q = *(const float4*)&Bs[kk][tx * 4];
      float aa[4] = {a.x, a.y, a.z, a.w};
      float qq[4] = {q.x, q.y, q.z, q.w};
#pragma unroll
      for (int i = 0; i < 4; i++)
#pragma unroll
        for (int j = 0; j < 4; j++) acc[i][j] += aa[i] * qq[j];
    }
  }
  float4 bzv = *(const float4*)(bz + bj * 64 + tx * 4);
  float* yout = YZ + ((size_t)b * N_ + bi * 64 + ty * 4) * (2 * C_) + bj * 64 + tx * 4;
#pragma unroll
  for (int i = 0; i < 4; i++) {
    float4 w = make_float4(acc[i][0] + bzv.x, acc[i][1] + bzv.y,
                           acc[i][2] + bzv.z, acc[i][3] + bzv.w);
    *(float4*)(yout + (size_t)i * (2 * C_)) = w;
  }
}

// ---- combine: out[n][o] = max_k leaky(Y[idx[n][k]][o] + Z[n][o]) ----
__global__ __launch_bounds__(384) void k_combine(const float* __restrict__ YZ,
                                                 const int* __restrict__ idx,
                                                 float* __restrict__ xout, int ldo) {
  __shared__ int sidx[4][K_];
  int n0 = blockIdx.x * 4, b = blockIdx.y, o = threadIdx.x;
  if (o < 4 * K_) {
    int q = o / K_, r = o % K_;
    sidx[q][r] = idx[((size_t)b * N_ + n0 + q) * K_ + r];
  }
  __syncthreads();
  const float* baseYZ = YZ + (size_t)b * N_ * (2 * C_);
#pragma unroll
  for (int nn = 0; nn < 4; nn++) {
    int n = n0 + nn;
    float z = baseYZ[n * (2 * C_) + C_ + o];
    float hmax = -INFINITY;
#pragma unroll
    for (int k = 0; k < K_; k++) {
      float y = baseYZ[sidx[nn][k] * (2 * C_) + o];
      float s = y + z;
      s = s > 0.f ? s : SLOPE_ * s;
      hmax = fmaxf(hmax, s);
    }
    xout[((size_t)b * N_ + n) * ldo + o] = hmax;
  }
}

// ---------------- final projection + BN + leaky + max over N ----------------
__global__ __launch_bounds__(384) void k_final(const float* __restrict__ cat,
                                               const float4* __restrict__ Wpq,
                                               const float* __restrict__ gp,
                                               const float* __restrict__ bp,
                                               const float* __restrict__ mp,
                                               const float* __restrict__ vp,
                                               unsigned* __restrict__ stage) {
  int nc = blockIdx.x, b = blockIdx.y, o = threadIdx.x;
  float sc = gp[o] * rsqrtf(vp[o] + EPS_);
  float bi_ = bp[o] - mp[o] * sc;
  float vmax = -INFINITY;
  for (int nn = 0; nn < 16; nn++) {
    const float4* row = (const float4*)(cat + ((size_t)b * N_ + nc * 16 + nn) * (3 * C_));
    float acc = 0.f;
    for (int c4 = 0; c4 < 3 * C_ / 4; c4++) {
      float4 xcv = row[c4];
      float4 w   = Wpq[c4 * C_ + o];
      acc += xcv.x * w.x + xcv.y * w.y + xcv.z * w.z + xcv.w * w.w;
    }
    float y = acc * sc + bi_;
    y = y > 0.f ? y : SLOPE_ * y;
    vmax = fmaxf(vmax, y);
  }
  atomicMax(stage + (size_t)b * C_ + o, fmap(vmax));
}

__global__ void k_init(unsigned* __restrict__ stage) {
  int t = blockIdx.x * 256 + threadIdx.x;
  if (t < B_ * C_) stage[t] = 0x007FFFFFu;  // fmap(-inf)
}

__global__ void k_unmap(const unsigned* __restrict__ stage, float* __restrict__ out) {
  int t = blockIdx.x * 256 + threadIdx.x;
  if (t < B_ * C_) out[t] = funmap(stage[t]);
}

// ---------------- host ----------------
extern "C" void kernel_launch(void* const* d_in, const int* in_sizes, int n_in,
                              void* d_out, int out_size, void* d_ws, size_t ws_size,
                              hipStream_t stream) {
  const float* x   = (const float*)d_in[0];
  const float* We[3] = {(const float*)d_in[2], (const float*)d_in[7], (const float*)d_in[12]};
  const float* g[3]  = {(const float*)d_in[3], (const float*)d_in[8], (const float*)d_in[13]};
  const float* bb[3] = {(const float*)d_in[4], (const float*)d_in[9], (const float*)d_in[14]};
  const float* m[3]  = {(const float*)d_in[5], (const float*)d_in[10], (const float*)d_in[15]};
  const float* v[3]  = {(const float*)d_in[6], (const float*)d_in[11], (const float*)d_in[16]};
  const float* Wp = (const float*)d_in[17];
  const float* gp = (const float*)d_in[18];
  const float* bp = (const float*)d_in[19];
  const float* mp = (const float*)d_in[20];
  const float* vp = (const float*)d_in[21];
  float* out = (float*)d_out;

  // workspace layout (float units)
  float* ws   = (float*)d_ws;
  float* xb   = ws;                                   // B*N*C          = 1,572,864
  float* xcat = xb + (size_t)B_ * N_ * C_;            // B*N*3C         = 4,718,592
  float* G    = xcat + (size_t)B_ * N_ * 3 * C_;      // B*N*N          = 8,388,608
  float* YZ   = G;                                    // aliases G (B*N*768 <= B*N*N)
  float* sq   = G + (size_t)B_ * N_ * N_;             // B*N
  int*   idx  = (int*)(sq + (size_t)B_ * N_);         // B*N*K
  float* Wt   = (float*)(idx + (size_t)B_ * N_ * K_); // C*768
  float* bz   = Wt + (size_t)C_ * 2 * C_;             // 768
  float4* Wpq = (float4*)(bz + 2 * C_);               // (3C/4)*C float4
  unsigned* stage = (unsigned*)(Wpq + (size_t)(3 * C_ / 4) * C_);

  k_prepwp<<<dim3(((3 * C_ / 4) * C_ + 255) / 256), 256, 0, stream>>>(Wp, Wpq);
  k_transpose<<<dim3(N_ / 32, C_ / 32, B_), 256, 0, stream>>>(x, xb);
  k_init<<<dim3((B_ * C_ + 255) / 256), 256, 0, stream>>>(stage);

  // three edge-conv layers
  for (int l = 0; l < 3; l++) {
    const float* xin;
    int ldx;
    if (l == 0) { xin = xb; ldx = C_; }
    else        { xin = xcat + (size_t)(l - 1) * C_; ldx = 3 * C_; }
    float* xout = xcat + (size_t)l * C_;

    k_rowsq<<<dim3(B_ * N_ / 4), 256, 0, stream>>>(xin, ldx, sq);
    k_gram<<<dim3(N_ / 64, N_ / 64, B_), 256, 0, stream>>>(xin, ldx, G);
    k_topk<<<dim3(N_, B_), 256, 0, stream>>>(G, sq, idx);
    // G fully consumed by k_topk; YZ aliases G from here on (stream-ordered)
    k_prepw2<<<dim3((C_ * 2 * C_ + 255) / 256), 256, 0, stream>>>(
        We[l], g[l], bb[l], m[l], v[l], Wt, bz);
    k_yzgemm<<<dim3(N_ / 64, 2 * C_ / 64, B_), 256, 0, stream>>>(xin, ldx, Wt, bz, YZ);
    k_combine<<<dim3(N_ / 4, B_), 384, 0, stream>>>(YZ, idx, xout, 3 * C_);
  }

  // final projection + global max
  k_final<<<dim3(N_ / 16, B_), 384, 0, stream>>>(xcat, Wpq, gp, bp, mp, vp, stage);
  k_unmap<<<dim3((B_ * C_ + 255) / 256), 256, 0, stream>>>(stage, out);
}

// Round 3
// 683.535 us; speedup vs baseline: 5.2612x; 1.4503x over previous
//
#include <hip/hip_runtime.h>
#include <cstdint>
#include <cstddef>

#define B_ 2
#define N_ 2048
#define C_ 384
#define K_ 20
#define EPS_ 1e-5f
#define SLOPE_ 0.2f

// ---------------- monotonic float<->uint mapping for atomicMax ----------------
__device__ __forceinline__ unsigned fmap(float f) {
  unsigned u = __float_as_uint(f);
  return (u & 0x80000000u) ? ~u : (u | 0x80000000u);
}
__device__ __forceinline__ float funmap(unsigned u) {
  unsigned bits = (u & 0x80000000u) ? (u ^ 0x80000000u) : ~u;
  return __uint_as_float(bits);
}

// ---------------- transpose x (B,C,N) -> xb (B,N,C) ----------------
__global__ __launch_bounds__(256) void k_transpose(const float* __restrict__ x,
                                                   float* __restrict__ xb) {
  __shared__ float tile[32][33];
  int bn = blockIdx.x;   // N/32
  int bc = blockIdx.y;   // C/32
  int b  = blockIdx.z;
  int tx = threadIdx.x & 31, ty = threadIdx.x >> 5;  // 32 x 8
  const float* src = x + ((size_t)b * C_ + bc * 32) * N_ + bn * 32;
#pragma unroll
  for (int j = 0; j < 32; j += 8)
    tile[ty + j][tx] = src[(size_t)(ty + j) * N_ + tx];
  __syncthreads();
  float* dst = xb + ((size_t)b * N_ + bn * 32) * C_ + bc * 32;
#pragma unroll
  for (int j = 0; j < 32; j += 8)
    dst[(size_t)(ty + j) * C_ + tx] = tile[tx][ty + j];
}

// ---------------- row squared norms ----------------
__global__ __launch_bounds__(256) void k_rowsq(const float* __restrict__ xin, int ldx,
                                               float* __restrict__ sq) {
  int row  = blockIdx.x * 4 + (threadIdx.x >> 6);  // b*N+n
  int lane = threadIdx.x & 63;
  const float* p = xin + (size_t)row * ldx;
  float v = 0.f;
#pragma unroll
  for (int i = 0; i < C_ / 64; i++) {
    float t = p[lane + i * 64];
    v += t * t;
  }
#pragma unroll
  for (int off = 32; off; off >>= 1) v += __shfl_xor(v, off, 64);
  if (lane == 0) sq[row] = v;
}

// ---- Gram matrix, symmetric: compute upper-triangle 64x64 tiles, mirror ----
__global__ __launch_bounds__(256) void k_gram(const float* __restrict__ xin, int ldx,
                                              float* __restrict__ G) {
  __shared__ __align__(16) float As[16][64];
  __shared__ __align__(16) float Bs[16][64];
  __shared__ __align__(16) float Ts[64][68];
  int b = blockIdx.z;
  int t = blockIdx.x;
  // decode triangular pair: p >= q
  int p = (int)((sqrtf(8.f * t + 1.f) - 1.f) * 0.5f);
  while ((p + 1) * (p + 2) / 2 <= t) p++;
  while (p * (p + 1) / 2 > t) p--;
  int q = t - p * (p + 1) / 2;
  int bi = q, bj = p;  // bi <= bj

  int tt = threadIdx.x;
  int tx = tt & 15, ty = tt >> 4;
  int lr = tt >> 2, lc4 = tt & 3;
  const float* base = xin + (size_t)b * N_ * ldx;
  float acc[4][4] = {};

  for (int kc = 0; kc < C_; kc += 16) {
    float4 av = *(const float4*)(base + (size_t)(bi * 64 + lr) * ldx + kc + lc4 * 4);
    float4 bv = *(const float4*)(base + (size_t)(bj * 64 + lr) * ldx + kc + lc4 * 4);
    __syncthreads();
    As[lc4 * 4 + 0][lr] = av.x; As[lc4 * 4 + 1][lr] = av.y;
    As[lc4 * 4 + 2][lr] = av.z; As[lc4 * 4 + 3][lr] = av.w;
    Bs[lc4 * 4 + 0][lr] = bv.x; Bs[lc4 * 4 + 1][lr] = bv.y;
    Bs[lc4 * 4 + 2][lr] = bv.z; Bs[lc4 * 4 + 3][lr] = bv.w;
    __syncthreads();
#pragma unroll
    for (int kk = 0; kk < 16; kk++) {
      float4 a = *(const float4*)&As[kk][ty * 4];
      float4 qv = *(const float4*)&Bs[kk][tx * 4];
      float aa[4] = {a.x, a.y, a.z, a.w};
      float qq[4] = {qv.x, qv.y, qv.z, qv.w};
#pragma unroll
      for (int i = 0; i < 4; i++)
#pragma unroll
        for (int j = 0; j < 4; j++) acc[i][j] += aa[i] * qq[j];
    }
  }
  // direct tile (bi rows, bj cols)
  float* gout = G + ((size_t)b * N_ + bi * 64 + ty * 4) * N_ + bj * 64 + tx * 4;
#pragma unroll
  for (int i = 0; i < 4; i++) {
    float4 w = make_float4(acc[i][0], acc[i][1], acc[i][2], acc[i][3]);
    *(float4*)(gout + (size_t)i * N_) = w;
  }
  // mirror tile (bj rows, bi cols) via LDS transpose
  if (bi != bj) {
#pragma unroll
    for (int i = 0; i < 4; i++)
#pragma unroll
      for (int j = 0; j < 4; j++)
        Ts[tx * 4 + j][ty * 4 + i] = acc[i][j];
    __syncthreads();
    float* gout2 = G + ((size_t)b * N_ + bj * 64 + lr) * N_ + bi * 64 + lc4 * 16;
#pragma unroll
    for (int jj = 0; jj < 4; jj++)
      *(float4*)(gout2 + jj * 4) = *(const float4*)&Ts[lr][lc4 * 16 + jj * 4];
  }
}

// ---------------- top-K (K=20) per row of neg_dist ----------------
__global__ __launch_bounds__(256) void k_topk(const float* __restrict__ G,
                                              const float* __restrict__ sq,
                                              int* __restrict__ idx) {
  __shared__ float vals[N_];
  __shared__ float wbv[4];
  __shared__ int wbi[4];
  int n = blockIdx.x, b = blockIdx.y, t = threadIdx.x;
  const float* grow = G + ((size_t)b * N_ + n) * N_;
  const float* sqb  = sq + (size_t)b * N_;
  float sqn = sqb[n];
#pragma unroll
  for (int i = 0; i < N_ / 256; i++) {
    int j = t + i * 256;
    vals[j] = 2.f * grow[j] - sqn - sqb[j];
  }
  __syncthreads();
  int* orow = idx + ((size_t)b * N_ + n) * K_;
  for (int it = 0; it < K_; it++) {
    float bv = -INFINITY;
    int  bi = 1 << 30;
#pragma unroll
    for (int i = 0; i < N_ / 256; i++) {
      int j  = t + i * 256;
      float v = vals[j];
      if (v > bv || (v == bv && j < bi)) { bv = v; bi = j; }
    }
#pragma unroll
    for (int off = 32; off; off >>= 1) {
      float v2 = __shfl_xor(bv, off, 64);
      int   i2 = __shfl_xor(bi, off, 64);
      if (v2 > bv || (v2 == bv && i2 < bi)) { bv = v2; bi = i2; }
    }
    int w = t >> 6;
    if ((t & 63) == 0) { wbv[w] = bv; wbi[w] = bi; }
    __syncthreads();
    if (t == 0) {
#pragma unroll
      for (int ww = 1; ww < 4; ww++)
        if (wbv[ww] > bv || (wbv[ww] == bv && wbi[ww] < bi)) { bv = wbv[ww]; bi = wbi[ww]; }
      orow[it] = bi;
      vals[bi] = -INFINITY;
    }
    __syncthreads();
  }
}

// ---- weight prep: build Wt[c][o2] (384 x 768), scale+bias folded ----
__global__ void k_prepw2(const float* __restrict__ We, const float* __restrict__ g,
                         const float* __restrict__ bb, const float* __restrict__ m,
                         const float* __restrict__ v, float* __restrict__ Wt,
                         float* __restrict__ bz) {
  int t = blockIdx.x * 256 + threadIdx.x;
  if (t >= C_ * 2 * C_) return;
  int c = t / (2 * C_), o2 = t % (2 * C_);
  int o = (o2 < C_) ? o2 : (o2 - C_);
  float sc = g[o] * rsqrtf(v[o] + EPS_);
  float w;
  if (o2 < C_) w = sc * We[(size_t)o * 2 * C_ + c];
  else         w = sc * (We[(size_t)o * 2 * C_ + C_ + c] - We[(size_t)o * 2 * C_ + c]);
  Wt[t] = w;
  if (t < 2 * C_) {
    int oo = (t < C_) ? -1 : t - C_;
    bz[t] = (oo < 0) ? 0.f : (bb[oo] - m[oo] * (g[oo] * rsqrtf(v[oo] + EPS_)));
  }
}

// ---- final-layer weight prep: Wt2[c][o] (1152 x 384), scale folded ----
__global__ void k_prepwp2(const float* __restrict__ Wp, const float* __restrict__ gp,
                          const float* __restrict__ bp, const float* __restrict__ mp,
                          const float* __restrict__ vp, float* __restrict__ Wt2,
                          float* __restrict__ bz2) {
  int t = blockIdx.x * 256 + threadIdx.x;
  if (t >= 3 * C_ * C_) return;
  int c = t / C_, o = t % C_;
  float sc = gp[o] * rsqrtf(vp[o] + EPS_);
  Wt2[t] = sc * Wp[(size_t)o * 3 * C_ + c];
  if (t < C_) {
    float sc2 = gp[t] * rsqrtf(vp[t] + EPS_);
    bz2[t] = bp[t] - mp[t] * sc2;
  }
}

// ---- YZ GEMM: YZ[b][n][o2] = sum_c X[n][c]*Wt[c][o2] + bz[o2] ----
__global__ __launch_bounds__(256) void k_yzgemm(const float* __restrict__ xin, int ldx,
                                                const float* __restrict__ Wt,
                                                const float* __restrict__ bz,
                                                float* __restrict__ YZ) {
  __shared__ __align__(16) float As[16][64];
  __shared__ __align__(16) float Bs[16][64];
  int bi = blockIdx.x, bj = blockIdx.y, b = blockIdx.z;
  int t  = threadIdx.x;
  int tx = t & 15, ty = t >> 4;
  int lrA = t >> 2, lc4A = t & 3;   // A loader
  int lrB = t >> 4, lc4B = t & 15;  // B loader
  const float* baseX = xin + (size_t)b * N_ * ldx;
  float acc[4][4] = {};

  for (int kc = 0; kc < C_; kc += 16) {
    float4 av = *(const float4*)(baseX + (size_t)(bi * 64 + lrA) * ldx + kc + lc4A * 4);
    float4 bv = *(const float4*)(Wt + (size_t)(kc + lrB) * (2 * C_) + bj * 64 + lc4B * 4);
    __syncthreads();
    As[lc4A * 4 + 0][lrA] = av.x; As[lc4A * 4 + 1][lrA] = av.y;
    As[lc4A * 4 + 2][lrA] = av.z; As[lc4A * 4 + 3][lrA] = av.w;
    *(float4*)&Bs[lrB][lc4B * 4] = bv;
    __syncthreads();
#pragma unroll
    for (int kk = 0; kk < 16; kk++) {
      float4 a = *(const float4*)&As[kk][ty * 4];
      float4 q = *(const float4*)&Bs[kk][tx * 4];
      float aa[4] = {a.x, a.y, a.z, a.w};
      float qq[4] = {q.x, q.y, q.z, q.w};
#pragma unroll
      for (int i = 0; i < 4; i++)
#pragma unroll
        for (int j = 0; j < 4; j++) acc[i][j] += aa[i] * qq[j];
    }
  }
  float4 bzv = *(const float4*)(bz + bj * 64 + tx * 4);
  float* yout = YZ + ((size_t)b * N_ + bi * 64 + ty * 4) * (2 * C_) + bj * 64 + tx * 4;
#pragma unroll
  for (int i = 0; i < 4; i++) {
    float4 w = make_float4(acc[i][0] + bzv.x, acc[i][1] + bzv.y,
                           acc[i][2] + bzv.z, acc[i][3] + bzv.w);
    *(float4*)(yout + (size_t)i * (2 * C_)) = w;
  }
}

// ---- combine: out[n][o] = max_k leaky(Y[idx[n][k]][o] + Z[n][o]) ----
__global__ __launch_bounds__(384) void k_combine(const float* __restrict__ YZ,
                                                 const int* __restrict__ idx,
                                                 float* __restrict__ xout, int ldo) {
  __shared__ int sidx[4][K_];
  int n0 = blockIdx.x * 4, b = blockIdx.y, o = threadIdx.x;
  if (o < 4 * K_) {
    int q = o / K_, r = o % K_;
    sidx[q][r] = idx[((size_t)b * N_ + n0 + q) * K_ + r];
  }
  __syncthreads();
  const float* baseYZ = YZ + (size_t)b * N_ * (2 * C_);
#pragma unroll
  for (int nn = 0; nn < 4; nn++) {
    int n = n0 + nn;
    float z = baseYZ[n * (2 * C_) + C_ + o];
    float hmax = -INFINITY;
#pragma unroll
    for (int k = 0; k < K_; k++) {
      float y = baseYZ[sidx[nn][k] * (2 * C_) + o];
      float s = y + z;
      s = s > 0.f ? s : SLOPE_ * s;
      hmax = fmaxf(hmax, s);
    }
    xout[((size_t)b * N_ + n) * ldo + o] = hmax;
  }
}

// ---- final GEMM (K=1152) + leaky + max over rows, atomicMax epilogue ----
__global__ __launch_bounds__(256) void k_fingemm(const float* __restrict__ cat,
                                                 const float* __restrict__ Wt2,
                                                 const float* __restrict__ bz2,
                                                 unsigned* __restrict__ stage) {
  __shared__ __align__(16) float As[16][64];
  __shared__ __align__(16) float Bs[16][64];
  __shared__ float Sm[16][64];
  int bi = blockIdx.x, bj = blockIdx.y, b = blockIdx.z;
  int t  = threadIdx.x;
  int tx = t & 15, ty = t >> 4;
  int lrA = t >> 2, lc4A = t & 3;
  int lrB = t >> 4, lc4B = t & 15;
  const float* baseX = cat + (size_t)b * N_ * (3 * C_);
  float acc[4][4] = {};

  for (int kc = 0; kc < 3 * C_; kc += 16) {
    float4 av = *(const float4*)(baseX + (size_t)(bi * 64 + lrA) * (3 * C_) + kc + lc4A * 4);
    float4 bv = *(const float4*)(Wt2 + (size_t)(kc + lrB) * C_ + bj * 64 + lc4B * 4);
    __syncthreads();
    As[lc4A * 4 + 0][lrA] = av.x; As[lc4A * 4 + 1][lrA] = av.y;
    As[lc4A * 4 + 2][lrA] = av.z; As[lc4A * 4 + 3][lrA] = av.w;
    *(float4*)&Bs[lrB][lc4B * 4] = bv;
    __syncthreads();
#pragma unroll
    for (int kk = 0; kk < 16; kk++) {
      float4 a = *(const float4*)&As[kk][ty * 4];
      float4 q = *(const float4*)&Bs[kk][tx * 4];
      float aa[4] = {a.x, a.y, a.z, a.w};
      float qq[4] = {q.x, q.y, q.z, q.w};
#pragma unroll
      for (int i = 0; i < 4; i++)
#pragma unroll
        for (int j = 0; j < 4; j++) acc[i][j] += aa[i] * qq[j];
    }
  }
  float4 bzv = *(const float4*)(bz2 + bj * 64 + tx * 4);
  float bzs[4] = {bzv.x, bzv.y, bzv.z, bzv.w};
#pragma unroll
  for (int j = 0; j < 4; j++) {
    float cm = -INFINITY;
#pragma unroll
    for (int i = 0; i < 4; i++) {
      float y = acc[i][j] + bzs[j];
      y = y > 0.f ? y : SLOPE_ * y;
      cm = fmaxf(cm, y);
    }
    Sm[ty][tx * 4 + j] = cm;
  }
  __syncthreads();
  if (t < 64) {
    float m = Sm[0][t];
#pragma unroll
    for (int ww = 1; ww < 16; ww++) m = fmaxf(m, Sm[ww][t]);
    atomicMax(stage + (size_t)b * C_ + bj * 64 + t, fmap(m));
  }
}

__global__ void k_init(unsigned* __restrict__ stage) {
  int t = blockIdx.x * 256 + threadIdx.x;
  if (t < B_ * C_) stage[t] = 0x007FFFFFu;  // fmap(-inf)
}

__global__ void k_unmap(const unsigned* __restrict__ stage, float* __restrict__ out) {
  int t = blockIdx.x * 256 + threadIdx.x;
  if (t < B_ * C_) out[t] = funmap(stage[t]);
}

// ---------------- host ----------------
extern "C" void kernel_launch(void* const* d_in, const int* in_sizes, int n_in,
                              void* d_out, int out_size, void* d_ws, size_t ws_size,
                              hipStream_t stream) {
  const float* x   = (const float*)d_in[0];
  const float* We[3] = {(const float*)d_in[2], (const float*)d_in[7], (const float*)d_in[12]};
  const float* g[3]  = {(const float*)d_in[3], (const float*)d_in[8], (const float*)d_in[13]};
  const float* bb[3] = {(const float*)d_in[4], (const float*)d_in[9], (const float*)d_in[14]};
  const float* m[3]  = {(const float*)d_in[5], (const float*)d_in[10], (const float*)d_in[15]};
  const float* v[3]  = {(const float*)d_in[6], (const float*)d_in[11], (const float*)d_in[16]};
  const float* Wp = (const float*)d_in[17];
  const float* gp = (const float*)d_in[18];
  const float* bp = (const float*)d_in[19];
  const float* mp = (const float*)d_in[20];
  const float* vp = (const float*)d_in[21];
  float* out = (float*)d_out;

  // workspace layout (float units)
  float* ws   = (float*)d_ws;
  float* xb   = ws;                                   // B*N*C
  float* xcat = xb + (size_t)B_ * N_ * C_;            // B*N*3C
  float* G    = xcat + (size_t)B_ * N_ * 3 * C_;      // B*N*N
  float* YZ   = G;                                    // aliases G
  float* sq   = G + (size_t)B_ * N_ * N_;             // B*N
  int*   idx  = (int*)(sq + (size_t)B_ * N_);         // B*N*K
  float* Wt   = (float*)(idx + (size_t)B_ * N_ * K_); // C*2C
  float* bz   = Wt + (size_t)C_ * 2 * C_;             // 2C
  float* Wt2  = bz + 2 * C_;                          // 3C*C
  float* bz2  = Wt2 + (size_t)3 * C_ * C_;            // C
  unsigned* stage = (unsigned*)(bz2 + C_);            // B*C

  k_prepwp2<<<dim3((3 * C_ * C_ + 255) / 256), 256, 0, stream>>>(Wp, gp, bp, mp, vp, Wt2, bz2);
  k_transpose<<<dim3(N_ / 32, C_ / 32, B_), 256, 0, stream>>>(x, xb);
  k_init<<<dim3((B_ * C_ + 255) / 256), 256, 0, stream>>>(stage);

  // three edge-conv layers
  for (int l = 0; l < 3; l++) {
    const float* xin;
    int ldx;
    if (l == 0) { xin = xb; ldx = C_; }
    else        { xin = xcat + (size_t)(l - 1) * C_; ldx = 3 * C_; }
    float* xout = xcat + (size_t)l * C_;

    k_rowsq<<<dim3(B_ * N_ / 4), 256, 0, stream>>>(xin, ldx, sq);
    k_gram<<<dim3((N_ / 64) * (N_ / 64 + 1) / 2, 1, B_), 256, 0, stream>>>(xin, ldx, G);
    k_topk<<<dim3(N_, B_), 256, 0, stream>>>(G, sq, idx);
    k_prepw2<<<dim3((C_ * 2 * C_ + 255) / 256), 256, 0, stream>>>(
        We[l], g[l], bb[l], m[l], v[l], Wt, bz);
    k_yzgemm<<<dim3(N_ / 64, 2 * C_ / 64, B_), 256, 0, stream>>>(xin, ldx, Wt, bz, YZ);
    k_combine<<<dim3(N_ / 4, B_), 384, 0, stream>>>(YZ, idx, xout, 3 * C_);
  }

  // final projection + global max (tiled GEMM + fused max)
  k_fingemm<<<dim3(N_ / 64, C_ / 64, B_), 256, 0, stream>>>(xcat, Wt2, bz2, stage);
  k_unmap<<<dim3((B_ * C_ + 255) / 256), 256, 0, stream>>>(stage, out);
}

// Round 4
// 545.740 us; speedup vs baseline: 6.5896x; 1.2525x over previous
//
#include <hip/hip_runtime.h>
#include <cstdint>
#include <cstddef>

#define B_ 2
#define N_ 2048
#define C_ 384
#define K_ 20
#define EPS_ 1e-5f
#define SLOPE_ 0.2f

// ---------------- monotonic float<->uint mapping for atomicMax ----------------
__device__ __forceinline__ unsigned fmap(float f) {
  unsigned u = __float_as_uint(f);
  return (u & 0x80000000u) ? ~u : (u | 0x80000000u);
}
__device__ __forceinline__ float funmap(unsigned u) {
  unsigned bits = (u & 0x80000000u) ? (u ^ 0x80000000u) : ~u;
  return __uint_as_float(bits);
}

// ---------------- transpose x (B,C,N) -> xb (B,N,C) ----------------
__global__ __launch_bounds__(256) void k_transpose(const float* __restrict__ x,
                                                   float* __restrict__ xb) {
  __shared__ float tile[32][33];
  int bn = blockIdx.x;   // N/32
  int bc = blockIdx.y;   // C/32
  int b  = blockIdx.z;
  int tx = threadIdx.x & 31, ty = threadIdx.x >> 5;  // 32 x 8
  const float* src = x + ((size_t)b * C_ + bc * 32) * N_ + bn * 32;
#pragma unroll
  for (int j = 0; j < 32; j += 8)
    tile[ty + j][tx] = src[(size_t)(ty + j) * N_ + tx];
  __syncthreads();
  float* dst = xb + ((size_t)b * N_ + bn * 32) * C_ + bc * 32;
#pragma unroll
  for (int j = 0; j < 32; j += 8)
    dst[(size_t)(ty + j) * C_ + tx] = tile[tx][ty + j];
}

// ---------------- row squared norms ----------------
__global__ __launch_bounds__(256) void k_rowsq(const float* __restrict__ xin, int ldx,
                                               float* __restrict__ sq) {
  int row  = blockIdx.x * 4 + (threadIdx.x >> 6);  // b*N+n
  int lane = threadIdx.x & 63;
  const float* p = xin + (size_t)row * ldx;
  float v = 0.f;
#pragma unroll
  for (int i = 0; i < C_ / 64; i++) {
    float t = p[lane + i * 64];
    v += t * t;
  }
#pragma unroll
  for (int off = 32; off; off >>= 1) v += __shfl_xor(v, off, 64);
  if (lane == 0) sq[row] = v;
}

// ---- Gram, symmetric, epilogue folds Gm = 2*G - sq[col] (per-row const dropped) ----
__global__ __launch_bounds__(256) void k_gram(const float* __restrict__ xin, int ldx,
                                              const float* __restrict__ sq,
                                              float* __restrict__ Gm) {
  __shared__ __align__(16) float As[16][64];
  __shared__ __align__(16) float Bs[16][64];
  __shared__ __align__(16) float Ts[64][68];
  int b = blockIdx.z;
  int t = blockIdx.x;
  // decode triangular pair: p >= q
  int p = (int)((sqrtf(8.f * t + 1.f) - 1.f) * 0.5f);
  while ((p + 1) * (p + 2) / 2 <= t) p++;
  while (p * (p + 1) / 2 > t) p--;
  int q = t - p * (p + 1) / 2;
  int bi = q, bj = p;  // bi <= bj

  int tt = threadIdx.x;
  int tx = tt & 15, ty = tt >> 4;
  int lr = tt >> 2, lc4 = tt & 3;
  const float* base = xin + (size_t)b * N_ * ldx;
  float acc[4][4] = {};

  for (int kc = 0; kc < C_; kc += 16) {
    float4 av = *(const float4*)(base + (size_t)(bi * 64 + lr) * ldx + kc + lc4 * 4);
    float4 bv = *(const float4*)(base + (size_t)(bj * 64 + lr) * ldx + kc + lc4 * 4);
    __syncthreads();
    As[lc4 * 4 + 0][lr] = av.x; As[lc4 * 4 + 1][lr] = av.y;
    As[lc4 * 4 + 2][lr] = av.z; As[lc4 * 4 + 3][lr] = av.w;
    Bs[lc4 * 4 + 0][lr] = bv.x; Bs[lc4 * 4 + 1][lr] = bv.y;
    Bs[lc4 * 4 + 2][lr] = bv.z; Bs[lc4 * 4 + 3][lr] = bv.w;
    __syncthreads();
#pragma unroll
    for (int kk = 0; kk < 16; kk++) {
      float4 a = *(const float4*)&As[kk][ty * 4];
      float4 qv = *(const float4*)&Bs[kk][tx * 4];
      float aa[4] = {a.x, a.y, a.z, a.w};
      float qq[4] = {qv.x, qv.y, qv.z, qv.w};
#pragma unroll
      for (int i = 0; i < 4; i++)
#pragma unroll
        for (int j = 0; j < 4; j++) acc[i][j] += aa[i] * qq[j];
    }
  }
  const float* sqb = sq + (size_t)b * N_;
  // direct tile (bi rows, bj cols): Gm = 2*acc - sq[col], col = bj*64+tx*4+j
  float4 sqBv = *(const float4*)(sqb + bj * 64 + tx * 4);
  float sqBs[4] = {sqBv.x, sqBv.y, sqBv.z, sqBv.w};
  float* gout = Gm + ((size_t)b * N_ + bi * 64 + ty * 4) * N_ + bj * 64 + tx * 4;
#pragma unroll
  for (int i = 0; i < 4; i++) {
    float4 w = make_float4(2.f * acc[i][0] - sqBs[0], 2.f * acc[i][1] - sqBs[1],
                           2.f * acc[i][2] - sqBs[2], 2.f * acc[i][3] - sqBs[3]);
    *(float4*)(gout + (size_t)i * N_) = w;
  }
  // mirror tile (bj rows, bi cols): col = bi*64+ty*4+i
  if (bi != bj) {
    float4 sqAv = *(const float4*)(sqb + bi * 64 + ty * 4);
    float sqAs[4] = {sqAv.x, sqAv.y, sqAv.z, sqAv.w};
#pragma unroll
    for (int i = 0; i < 4; i++)
#pragma unroll
      for (int j = 0; j < 4; j++)
        Ts[tx * 4 + j][ty * 4 + i] = 2.f * acc[i][j] - sqAs[i];
    __syncthreads();
    float* gout2 = Gm + ((size_t)b * N_ + bj * 64 + lr) * N_ + bi * 64 + lc4 * 16;
#pragma unroll
    for (int jj = 0; jj < 4; jj++)
      *(float4*)(gout2 + jj * 4) = *(const float4*)&Ts[lr][lc4 * 16 + jj * 4];
  }
}

// ---- top-K: wave-per-row, register-resident iterative extraction ----
// lane owns columns j = q*256 + lane*4 + i  (q=0..7, i=0..3)
__global__ __launch_bounds__(256) void k_topk(const float* __restrict__ Gm,
                                              int* __restrict__ idx) {
  int lane = threadIdx.x & 63, wv = threadIdx.x >> 6;
  int n = blockIdx.x * 4 + wv, b = blockIdx.y;
  const float4* grow = (const float4*)(Gm + ((size_t)b * N_ + n) * N_);
  float va[32];
#pragma unroll
  for (int q = 0; q < 8; q++) {
    float4 t4 = grow[q * 64 + lane];
    va[q * 4 + 0] = t4.x; va[q * 4 + 1] = t4.y;
    va[q * 4 + 2] = t4.z; va[q * 4 + 3] = t4.w;
  }
  // local argmax (ascending j scan -> lowest index kept on ties)
  float bv = va[0];
  int bj = lane * 4;
#pragma unroll
  for (int s = 1; s < 32; s++) {
    int j = (s >> 2) * 256 + lane * 4 + (s & 3);
    if (va[s] > bv) { bv = va[s]; bj = j; }
  }
  int mysel = 0;
  for (int it = 0; it < K_; it++) {
    float gv = bv;
    int gj = bj;
#pragma unroll
    for (int off = 32; off; off >>= 1) {
      float v2 = __shfl_xor(gv, off, 64);
      int j2 = __shfl_xor(gj, off, 64);
      if (v2 > gv || (v2 == gv && j2 < gj)) { gv = v2; gj = j2; }
    }
    if (lane == it) mysel = gj;
    if (bj == gj) {  // this lane owns the winner: remove + rescan
      bv = -INFINITY;
      bj = 0x7FFFFFFF;
#pragma unroll
      for (int s = 0; s < 32; s++) {
        int j = (s >> 2) * 256 + lane * 4 + (s & 3);
        float v = (j == gj) ? -INFINITY : va[s];
        va[s] = v;
        if (v > bv) { bv = v; bj = j; }
      }
    }
  }
  if (lane < K_) idx[((size_t)b * N_ + n) * K_ + lane] = mysel;
}

// ---- weight prep: build Wt[c][o2] (384 x 768), scale+bias folded ----
__global__ void k_prepw2(const float* __restrict__ We, const float* __restrict__ g,
                         const float* __restrict__ bb, const float* __restrict__ m,
                         const float* __restrict__ v, float* __restrict__ Wt,
                         float* __restrict__ bz) {
  int t = blockIdx.x * 256 + threadIdx.x;
  if (t >= C_ * 2 * C_) return;
  int c = t / (2 * C_), o2 = t % (2 * C_);
  int o = (o2 < C_) ? o2 : (o2 - C_);
  float sc = g[o] * rsqrtf(v[o] + EPS_);
  float w;
  if (o2 < C_) w = sc * We[(size_t)o * 2 * C_ + c];
  else         w = sc * (We[(size_t)o * 2 * C_ + C_ + c] - We[(size_t)o * 2 * C_ + c]);
  Wt[t] = w;
  if (t < 2 * C_) {
    int oo = (t < C_) ? -1 : t - C_;
    bz[t] = (oo < 0) ? 0.f : (bb[oo] - m[oo] * (g[oo] * rsqrtf(v[oo] + EPS_)));
  }
}

// ---- final-layer weight prep: Wt2[c][o] (1152 x 384), scale folded ----
__global__ void k_prepwp2(const float* __restrict__ Wp, const float* __restrict__ gp,
                          const float* __restrict__ bp, const float* __restrict__ mp,
                          const float* __restrict__ vp, float* __restrict__ Wt2,
                          float* __restrict__ bz2) {
  int t = blockIdx.x * 256 + threadIdx.x;
  if (t >= 3 * C_ * C_) return;
  int c = t / C_, o = t % C_;
  float sc = gp[o] * rsqrtf(vp[o] + EPS_);
  Wt2[t] = sc * Wp[(size_t)o * 3 * C_ + c];
  if (t < C_) {
    float sc2 = gp[t] * rsqrtf(vp[t] + EPS_);
    bz2[t] = bp[t] - mp[t] * sc2;
  }
}

// ---- YZ GEMM: YZ[b][n][o2] = sum_c X[n][c]*Wt[c][o2] + bz[o2] ----
__global__ __launch_bounds__(256) void k_yzgemm(const float* __restrict__ xin, int ldx,
                                                const float* __restrict__ Wt,
                                                const float* __restrict__ bz,
                                                float* __restrict__ YZ) {
  __shared__ __align__(16) float As[16][64];
  __shared__ __align__(16) float Bs[16][64];
  int bi = blockIdx.x, bj = blockIdx.y, b = blockIdx.z;
  int t  = threadIdx.x;
  int tx = t & 15, ty = t >> 4;
  int lrA = t >> 2, lc4A = t & 3;   // A loader
  int lrB = t >> 4, lc4B = t & 15;  // B loader
  const float* baseX = xin + (size_t)b * N_ * ldx;
  float acc[4][4] = {};

  for (int kc = 0; kc < C_; kc += 16) {
    float4 av = *(const float4*)(baseX + (size_t)(bi * 64 + lrA) * ldx + kc + lc4A * 4);
    float4 bv = *(const float4*)(Wt + (size_t)(kc + lrB) * (2 * C_) + bj * 64 + lc4B * 4);
    __syncthreads();
    As[lc4A * 4 + 0][lrA] = av.x; As[lc4A * 4 + 1][lrA] = av.y;
    As[lc4A * 4 + 2][lrA] = av.z; As[lc4A * 4 + 3][lrA] = av.w;
    *(float4*)&Bs[lrB][lc4B * 4] = bv;
    __syncthreads();
#pragma unroll
    for (int kk = 0; kk < 16; kk++) {
      float4 a = *(const float4*)&As[kk][ty * 4];
      float4 q = *(const float4*)&Bs[kk][tx * 4];
      float aa[4] = {a.x, a.y, a.z, a.w};
      float qq[4] = {q.x, q.y, q.z, q.w};
#pragma unroll
      for (int i = 0; i < 4; i++)
#pragma unroll
        for (int j = 0; j < 4; j++) acc[i][j] += aa[i] * qq[j];
    }
  }
  float4 bzv = *(const float4*)(bz + bj * 64 + tx * 4);
  float* yout = YZ + ((size_t)b * N_ + bi * 64 + ty * 4) * (2 * C_) + bj * 64 + tx * 4;
#pragma unroll
  for (int i = 0; i < 4; i++) {
    float4 w = make_float4(acc[i][0] + bzv.x, acc[i][1] + bzv.y,
                           acc[i][2] + bzv.z, acc[i][3] + bzv.w);
    *(float4*)(yout + (size_t)i * (2 * C_)) = w;
  }
}

// ---- combine: out[n][o] = max_k leaky(Y[idx[n][k]][o] + Z[n][o]) ----
__global__ __launch_bounds__(384) void k_combine(const float* __restrict__ YZ,
                                                 const int* __restrict__ idx,
                                                 float* __restrict__ xout, int ldo) {
  __shared__ int sidx[4][K_];
  int n0 = blockIdx.x * 4, b = blockIdx.y, o = threadIdx.x;
  if (o < 4 * K_) {
    int q = o / K_, r = o % K_;
    sidx[q][r] = idx[((size_t)b * N_ + n0 + q) * K_ + r];
  }
  __syncthreads();
  const float* baseYZ = YZ + (size_t)b * N_ * (2 * C_);
#pragma unroll
  for (int nn = 0; nn < 4; nn++) {
    int n = n0 + nn;
    float z = baseYZ[n * (2 * C_) + C_ + o];
    float hmax = -INFINITY;
#pragma unroll
    for (int k = 0; k < K_; k++) {
      float y = baseYZ[sidx[nn][k] * (2 * C_) + o];
      float s = y + z;
      s = s > 0.f ? s : SLOPE_ * s;
      hmax = fmaxf(hmax, s);
    }
    xout[((size_t)b * N_ + n) * ldo + o] = hmax;
  }
}

// ---- final GEMM (K=1152) + leaky + max over rows, atomicMax epilogue ----
__global__ __launch_bounds__(256) void k_fingemm(const float* __restrict__ cat,
                                                 const float* __restrict__ Wt2,
                                                 const float* __restrict__ bz2,
                                                 unsigned* __restrict__ stage) {
  __shared__ __align__(16) float As[16][64];
  __shared__ __align__(16) float Bs[16][64];
  __shared__ float Sm[16][64];
  int bi = blockIdx.x, bj = blockIdx.y, b = blockIdx.z;
  int t  = threadIdx.x;
  int tx = t & 15, ty = t >> 4;
  int lrA = t >> 2, lc4A = t & 3;
  int lrB = t >> 4, lc4B = t & 15;
  const float* baseX = cat + (size_t)b * N_ * (3 * C_);
  float acc[4][4] = {};

  for (int kc = 0; kc < 3 * C_; kc += 16) {
    float4 av = *(const float4*)(baseX + (size_t)(bi * 64 + lrA) * (3 * C_) + kc + lc4A * 4);
    float4 bv = *(const float4*)(Wt2 + (size_t)(kc + lrB) * C_ + bj * 64 + lc4B * 4);
    __syncthreads();
    As[lc4A * 4 + 0][lrA] = av.x; As[lc4A * 4 + 1][lrA] = av.y;
    As[lc4A * 4 + 2][lrA] = av.z; As[lc4A * 4 + 3][lrA] = av.w;
    *(float4*)&Bs[lrB][lc4B * 4] = bv;
    __syncthreads();
#pragma unroll
    for (int kk = 0; kk < 16; kk++) {
      float4 a = *(const float4*)&As[kk][ty * 4];
      float4 q = *(const float4*)&Bs[kk][tx * 4];
      float aa[4] = {a.x, a.y, a.z, a.w};
      float qq[4] = {q.x, q.y, q.z, q.w};
#pragma unroll
      for (int i = 0; i < 4; i++)
#pragma unroll
        for (int j = 0; j < 4; j++) acc[i][j] += aa[i] * qq[j];
    }
  }
  float4 bzv = *(const float4*)(bz2 + bj * 64 + tx * 4);
  float bzs[4] = {bzv.x, bzv.y, bzv.z, bzv.w};
#pragma unroll
  for (int j = 0; j < 4; j++) {
    float cm = -INFINITY;
#pragma unroll
    for (int i = 0; i < 4; i++) {
      float y = acc[i][j] + bzs[j];
      y = y > 0.f ? y : SLOPE_ * y;
      cm = fmaxf(cm, y);
    }
    Sm[ty][tx * 4 + j] = cm;
  }
  __syncthreads();
  if (t < 64) {
    float m = Sm[0][t];
#pragma unroll
    for (int ww = 1; ww < 16; ww++) m = fmaxf(m, Sm[ww][t]);
    atomicMax(stage + (size_t)b * C_ + bj * 64 + t, fmap(m));
  }
}

__global__ void k_init(unsigned* __restrict__ stage) {
  int t = blockIdx.x * 256 + threadIdx.x;
  if (t < B_ * C_) stage[t] = 0x007FFFFFu;  // fmap(-inf)
}

__global__ void k_unmap(const unsigned* __restrict__ stage, float* __restrict__ out) {
  int t = blockIdx.x * 256 + threadIdx.x;
  if (t < B_ * C_) out[t] = funmap(stage[t]);
}

// ---------------- host ----------------
extern "C" void kernel_launch(void* const* d_in, const int* in_sizes, int n_in,
                              void* d_out, int out_size, void* d_ws, size_t ws_size,
                              hipStream_t stream) {
  const float* x   = (const float*)d_in[0];
  const float* We[3] = {(const float*)d_in[2], (const float*)d_in[7], (const float*)d_in[12]};
  const float* g[3]  = {(const float*)d_in[3], (const float*)d_in[8], (const float*)d_in[13]};
  const float* bb[3] = {(const float*)d_in[4], (const float*)d_in[9], (const float*)d_in[14]};
  const float* m[3]  = {(const float*)d_in[5], (const float*)d_in[10], (const float*)d_in[15]};
  const float* v[3]  = {(const float*)d_in[6], (const float*)d_in[11], (const float*)d_in[16]};
  const float* Wp = (const float*)d_in[17];
  const float* gp = (const float*)d_in[18];
  const float* bp = (const float*)d_in[19];
  const float* mp = (const float*)d_in[20];
  const float* vp = (const float*)d_in[21];
  float* out = (float*)d_out;

  // workspace layout (float units)
  float* ws   = (float*)d_ws;
  float* xb   = ws;                                   // B*N*C
  float* xcat = xb + (size_t)B_ * N_ * C_;            // B*N*3C
  float* G    = xcat + (size_t)B_ * N_ * 3 * C_;      // B*N*N
  float* YZ   = G;                                    // aliases G
  float* sq   = G + (size_t)B_ * N_ * N_;             // B*N
  int*   idx  = (int*)(sq + (size_t)B_ * N_);         // B*N*K
  float* Wt   = (float*)(idx + (size_t)B_ * N_ * K_); // C*2C
  float* bz   = Wt + (size_t)C_ * 2 * C_;             // 2C
  float* Wt2  = bz + 2 * C_;                          // 3C*C
  float* bz2  = Wt2 + (size_t)3 * C_ * C_;            // C
  unsigned* stage = (unsigned*)(bz2 + C_);            // B*C

  k_prepwp2<<<dim3((3 * C_ * C_ + 255) / 256), 256, 0, stream>>>(Wp, gp, bp, mp, vp, Wt2, bz2);
  k_transpose<<<dim3(N_ / 32, C_ / 32, B_), 256, 0, stream>>>(x, xb);
  k_init<<<dim3((B_ * C_ + 255) / 256), 256, 0, stream>>>(stage);

  // three edge-conv layers
  for (int l = 0; l < 3; l++) {
    const float* xin;
    int ldx;
    if (l == 0) { xin = xb; ldx = C_; }
    else        { xin = xcat + (size_t)(l - 1) * C_; ldx = 3 * C_; }
    float* xout = xcat + (size_t)l * C_;

    k_rowsq<<<dim3(B_ * N_ / 4), 256, 0, stream>>>(xin, ldx, sq);
    k_gram<<<dim3((N_ / 64) * (N_ / 64 + 1) / 2, 1, B_), 256, 0, stream>>>(xin, ldx, sq, G);
    k_topk<<<dim3(N_ / 4, B_), 256, 0, stream>>>(G, idx);
    k_prepw2<<<dim3((C_ * 2 * C_ + 255) / 256), 256, 0, stream>>>(
        We[l], g[l], bb[l], m[l], v[l], Wt, bz);
    k_yzgemm<<<dim3(N_ / 64, 2 * C_ / 64, B_), 256, 0, stream>>>(xin, ldx, Wt, bz, YZ);
    k_combine<<<dim3(N_ / 4, B_), 384, 0, stream>>>(YZ, idx, xout, 3 * C_);
  }

  // final projection + global max (tiled GEMM + fused max)
  k_fingemm<<<dim3(N_ / 64, C_ / 64, B_), 256, 0, stream>>>(xcat, Wt2, bz2, stage);
  k_unmap<<<dim3((B_ * C_ + 255) / 256), 256, 0, stream>>>(stage, out);
}

// Round 6
// 527.435 us; speedup vs baseline: 6.8183x; 1.0347x over previous
//
#include <hip/hip_runtime.h>
#include <hip/hip_bf16.h>
#include <cstdint>
#include <cstddef>

#define B_ 2
#define N_ 2048
#define C_ 384
#define K_ 20
#define EPS_ 1e-5f
#define SLOPE_ 0.2f

typedef __attribute__((ext_vector_type(8))) short short8;
typedef __attribute__((ext_vector_type(4))) float floatx4;

#define MFMA(a, b, c) __builtin_amdgcn_mfma_f32_16x16x32_bf16((a), (b), (c), 0, 0, 0)

// ---------------- helpers ----------------
__device__ __forceinline__ unsigned fmap(float f) {
  unsigned u = __float_as_uint(f);
  return (u & 0x80000000u) ? ~u : (u | 0x80000000u);
}
__device__ __forceinline__ float funmap(unsigned u) {
  unsigned bits = (u & 0x80000000u) ? (u ^ 0x80000000u) : ~u;
  return __uint_as_float(bits);
}
__device__ __forceinline__ short f2b(float f) {  // RNE fp32->bf16 bits
  __hip_bfloat16 h = __float2bfloat16(f);
  unsigned short u;
  __builtin_memcpy(&u, &h, 2);
  return (short)u;
}
__device__ __forceinline__ float b2f(short s) {
  unsigned u = ((unsigned)(unsigned short)s) << 16;
  return __uint_as_float(u);
}

// ---- transpose x (B,C,N) -> H0/L0 (B,N,C) bf16 split ----
__global__ __launch_bounds__(256) void k_transpose(const float* __restrict__ x,
                                                   short* __restrict__ H0,
                                                   short* __restrict__ L0) {
  __shared__ float tile[32][33];
  int bn = blockIdx.x, bc = blockIdx.y, b = blockIdx.z;
  int tx = threadIdx.x & 31, ty = threadIdx.x >> 5;  // 32 x 8
  const float* src = x + ((size_t)b * C_ + bc * 32) * N_ + bn * 32;
#pragma unroll
  for (int j = 0; j < 32; j += 8)
    tile[ty + j][tx] = src[(size_t)(ty + j) * N_ + tx];
  __syncthreads();
#pragma unroll
  for (int j = 0; j < 32; j += 8) {
    float val = tile[tx][ty + j];
    short hb = f2b(val);
    short lb = f2b(val - b2f(hb));
    size_t off = ((size_t)b * N_ + bn * 32 + ty + j) * C_ + bc * 32 + tx;
    H0[off] = hb;
    L0[off] = lb;
  }
}

// ---- row squared norms from H+L ----
__global__ __launch_bounds__(256) void k_rowsq(const short* __restrict__ H,
                                               const short* __restrict__ L,
                                               int ldh, int coff,
                                               float* __restrict__ sq) {
  int row  = blockIdx.x * 4 + (threadIdx.x >> 6);  // b*N+n
  int lane = threadIdx.x & 63;
  const short* ph = H + (size_t)row * ldh + coff;
  const short* pl = L + (size_t)row * ldh + coff;
  float v = 0.f;
#pragma unroll
  for (int i = 0; i < C_ / 64; i++) {
    int j = lane + i * 64;
    float t = b2f(ph[j]) + b2f(pl[j]);
    v += t * t;
  }
#pragma unroll
  for (int off = 32; off; off >>= 1) v += __shfl_xor(v, off, 64);
  if (lane == 0) sq[row] = v;
}

// ---- Gram via split-bf16 MFMA: Gm = 2*(H+L)_i.(H+L)_j - sq[col], symmetric tiles ----
__global__ __launch_bounds__(256) void k_gram(const short* __restrict__ H,
                                              const short* __restrict__ L,
                                              int ldh, int coff,
                                              const float* __restrict__ sq,
                                              float* __restrict__ Gm) {
  __shared__ __align__(16) float Ts[64][68];
  int b = blockIdx.z;
  int t = blockIdx.x;
  int p = (int)((sqrtf(8.f * t + 1.f) - 1.f) * 0.5f);
  while ((p + 1) * (p + 2) / 2 <= t) p++;
  while (p * (p + 1) / 2 > t) p--;
  int q = t - p * (p + 1) / 2;
  int bi = q, bj = p;  // bi <= bj

  int tid = threadIdx.x, lane = tid & 63, w = tid >> 6;
  int wr = w >> 1, wc = w & 1;
  int fr = lane & 15, fk = (lane >> 4) << 3, r0 = (lane >> 4) << 2;

  const short* Hb = H + (size_t)b * N_ * ldh + coff;
  const short* Lb = L + (size_t)b * N_ * ldh + coff;
  int rA = bi * 64 + wr * 32, rB = bj * 64 + wc * 32;

  floatx4 acc00 = {0.f, 0.f, 0.f, 0.f}, acc01 = {0.f, 0.f, 0.f, 0.f};
  floatx4 acc10 = {0.f, 0.f, 0.f, 0.f}, acc11 = {0.f, 0.f, 0.f, 0.f};

  for (int kc = 0; kc < C_; kc += 32) {
    short8 ah0 = *(const short8*)(Hb + (size_t)(rA + fr) * ldh + kc + fk);
    short8 ah1 = *(const short8*)(Hb + (size_t)(rA + 16 + fr) * ldh + kc + fk);
    short8 bh0 = *(const short8*)(Hb + (size_t)(rB + fr) * ldh + kc + fk);
    short8 bh1 = *(const short8*)(Hb + (size_t)(rB + 16 + fr) * ldh + kc + fk);
    short8 al0 = *(const short8*)(Lb + (size_t)(rA + fr) * ldh + kc + fk);
    short8 al1 = *(const short8*)(Lb + (size_t)(rA + 16 + fr) * ldh + kc + fk);
    short8 bl0 = *(const short8*)(Lb + (size_t)(rB + fr) * ldh + kc + fk);
    short8 bl1 = *(const short8*)(Lb + (size_t)(rB + 16 + fr) * ldh + kc + fk);
    acc00 = MFMA(ah0, bh0, acc00); acc00 = MFMA(ah0, bl0, acc00); acc00 = MFMA(al0, bh0, acc00);
    acc01 = MFMA(ah0, bh1, acc01); acc01 = MFMA(ah0, bl1, acc01); acc01 = MFMA(al0, bh1, acc01);
    acc10 = MFMA(ah1, bh0, acc10); acc10 = MFMA(ah1, bl0, acc10); acc10 = MFMA(al1, bh0, acc10);
    acc11 = MFMA(ah1, bh1, acc11); acc11 = MFMA(ah1, bl1, acc11); acc11 = MFMA(al1, bh1, acc11);
  }

  const float* sqb = sq + (size_t)b * N_;
  float sqB0 = sqb[bj * 64 + wc * 32 + fr];
  float sqB1 = sqb[bj * 64 + wc * 32 + 16 + fr];
  float* gbase = Gm + (size_t)b * N_ * N_;
  // direct tile (rows bi, cols bj); C/D: col=lane&15, row=(lane>>4)*4+i
#pragma unroll
  for (int i = 0; i < 4; i++) {
    float* grp0 = gbase + (size_t)(bi * 64 + wr * 32 + r0 + i) * N_ + bj * 64 + wc * 32;
    grp0[fr]      = 2.f * acc00[i] - sqB0;
    grp0[16 + fr] = 2.f * acc01[i] - sqB1;
    float* grp1 = gbase + (size_t)(bi * 64 + wr * 32 + 16 + r0 + i) * N_ + bj * 64 + wc * 32;
    grp1[fr]      = 2.f * acc10[i] - sqB0;
    grp1[16 + fr] = 2.f * acc11[i] - sqB1;
  }
  // mirror tile (rows bj, cols bi) via LDS transpose
  if (bi != bj) {
#pragma unroll
    for (int i = 0; i < 4; i++) {
      float sqA0 = sqb[bi * 64 + wr * 32 + r0 + i];
      float sqA1 = sqb[bi * 64 + wr * 32 + 16 + r0 + i];
      Ts[wc * 32 + fr][wr * 32 + r0 + i]           = 2.f * acc00[i] - sqA0;
      Ts[wc * 32 + 16 + fr][wr * 32 + r0 + i]      = 2.f * acc01[i] - sqA0;
      Ts[wc * 32 + fr][wr * 32 + 16 + r0 + i]      = 2.f * acc10[i] - sqA1;
      Ts[wc * 32 + 16 + fr][wr * 32 + 16 + r0 + i] = 2.f * acc11[i] - sqA1;
    }
    __syncthreads();
    int lr = tid >> 2, lc4 = tid & 3;
    float* g2 = gbase + (size_t)(bj * 64 + lr) * N_ + bi * 64 + lc4 * 16;
#pragma unroll
    for (int jj = 0; jj < 4; jj++)
      *(float4*)(g2 + jj * 4) = *(const float4*)&Ts[lr][lc4 * 16 + jj * 4];
  }
}

// ---- top-K: wave-per-row, register-resident iterative extraction ----
__global__ __launch_bounds__(256) void k_topk(const float* __restrict__ Gm,
                                              int* __restrict__ idx) {
  int lane = threadIdx.x & 63, wv = threadIdx.x >> 6;
  int n = blockIdx.x * 4 + wv, b = blockIdx.y;
  const float4* grow = (const float4*)(Gm + ((size_t)b * N_ + n) * N_);
  float va[32];
#pragma unroll
  for (int q = 0; q < 8; q++) {
    float4 t4 = grow[q * 64 + lane];
    va[q * 4 + 0] = t4.x; va[q * 4 + 1] = t4.y;
    va[q * 4 + 2] = t4.z; va[q * 4 + 3] = t4.w;
  }
  float bv = va[0];
  int bj = lane * 4;
#pragma unroll
  for (int s = 1; s < 32; s++) {
    int j = (s >> 2) * 256 + lane * 4 + (s & 3);
    if (va[s] > bv) { bv = va[s]; bj = j; }
  }
  int mysel = 0;
  for (int it = 0; it < K_; it++) {
    float gv = bv;
    int gj = bj;
#pragma unroll
    for (int off = 32; off; off >>= 1) {
      float v2 = __shfl_xor(gv, off, 64);
      int j2 = __shfl_xor(gj, off, 64);
      if (v2 > gv || (v2 == gv && j2 < gj)) { gv = v2; gj = j2; }
    }
    if (lane == it) mysel = gj;
    if (bj == gj) {
      bv = -INFINITY;
      bj = 0x7FFFFFFF;
#pragma unroll
      for (int s = 0; s < 32; s++) {
        int j = (s >> 2) * 256 + lane * 4 + (s & 3);
        float v = (j == gj) ? -INFINITY : va[s];
        va[s] = v;
        if (v > bv) { bv = v; bj = j; }
      }
    }
  }
  if (lane < K_) idx[((size_t)b * N_ + n) * K_ + lane] = mysel;
}

// ---- edge weight prep: WH/WL[o2][c] bf16 split (768x384), scale folded; bz ----
__global__ void k_prepw(const float* __restrict__ We, const float* __restrict__ g,
                        const float* __restrict__ bb, const float* __restrict__ m,
                        const float* __restrict__ v, short* __restrict__ WH,
                        short* __restrict__ WL, float* __restrict__ bz) {
  int t = blockIdx.x * 256 + threadIdx.x;
  if (t >= 2 * C_ * C_) return;
  int o2 = t / C_, c = t % C_;
  int o = (o2 < C_) ? o2 : (o2 - C_);
  float sc = g[o] * rsqrtf(v[o] + EPS_);
  float w = (o2 < C_) ? sc * We[(size_t)o * 2 * C_ + c]
                      : sc * (We[(size_t)o * 2 * C_ + C_ + c] - We[(size_t)o * 2 * C_ + c]);
  short hb = f2b(w);
  WH[t] = hb;
  WL[t] = f2b(w - b2f(hb));
  if (t < 2 * C_) {
    bz[t] = (t < C_) ? 0.f
                     : (bb[t - C_] - m[t - C_] * (g[t - C_] * rsqrtf(v[t - C_] + EPS_)));
  }
}

// ---- final weight prep: WpH/WpL[o][cc] bf16 split (384x1152), scale folded; bz2 ----
__global__ void k_prepwp(const float* __restrict__ Wp, const float* __restrict__ gp,
                         const float* __restrict__ bp, const float* __restrict__ mp,
                         const float* __restrict__ vp, short* __restrict__ WpH,
                         short* __restrict__ WpL, float* __restrict__ bz2) {
  int t = blockIdx.x * 256 + threadIdx.x;
  if (t >= C_ * 3 * C_) return;
  int o = t / (3 * C_);
  float sc = gp[o] * rsqrtf(vp[o] + EPS_);
  float w = sc * Wp[t];
  short hb = f2b(w);
  WpH[t] = hb;
  WpL[t] = f2b(w - b2f(hb));
  if (t < C_) {
    float s2 = gp[t] * rsqrtf(vp[t] + EPS_);
    bz2[t] = bp[t] - mp[t] * s2;
  }
}

// ---- YZ GEMM (split MFMA): YZ[b][n][o2] = (H+L)[n,:].(WH+WL)[o2,:] + bz[o2] ----
__global__ __launch_bounds__(256) void k_yzgemm(const short* __restrict__ H,
                                                const short* __restrict__ L,
                                                int ldh, int coff,
                                                const short* __restrict__ WH,
                                                const short* __restrict__ WL,
                                                const float* __restrict__ bz,
                                                float* __restrict__ YZ) {
  int bi = blockIdx.x, bj = blockIdx.y, b = blockIdx.z;
  int tid = threadIdx.x, lane = tid & 63, w = tid >> 6;
  int wr = w >> 1, wc = w & 1;
  int fr = lane & 15, fk = (lane >> 4) << 3, r0 = (lane >> 4) << 2;
  const short* Hb = H + (size_t)b * N_ * ldh + coff;
  const short* Lb = L + (size_t)b * N_ * ldh + coff;
  int rA = bi * 64 + wr * 32, rW = bj * 64 + wc * 32;

  floatx4 acc00 = {0.f, 0.f, 0.f, 0.f}, acc01 = {0.f, 0.f, 0.f, 0.f};
  floatx4 acc10 = {0.f, 0.f, 0.f, 0.f}, acc11 = {0.f, 0.f, 0.f, 0.f};

  for (int kc = 0; kc < C_; kc += 32) {
    short8 ah0 = *(const short8*)(Hb + (size_t)(rA + fr) * ldh + kc + fk);
    short8 ah1 = *(const short8*)(Hb + (size_t)(rA + 16 + fr) * ldh + kc + fk);
    short8 al0 = *(const short8*)(Lb + (size_t)(rA + fr) * ldh + kc + fk);
    short8 al1 = *(const short8*)(Lb + (size_t)(rA + 16 + fr) * ldh + kc + fk);
    short8 wh0 = *(const short8*)(WH + (size_t)(rW + fr) * C_ + kc + fk);
    short8 wh1 = *(const short8*)(WH + (size_t)(rW + 16 + fr) * C_ + kc + fk);
    short8 wl0 = *(const short8*)(WL + (size_t)(rW + fr) * C_ + kc + fk);
    short8 wl1 = *(const short8*)(WL + (size_t)(rW + 16 + fr) * C_ + kc + fk);
    acc00 = MFMA(ah0, wh0, acc00); acc00 = MFMA(ah0, wl0, acc00); acc00 = MFMA(al0, wh0, acc00);
    acc01 = MFMA(ah0, wh1, acc01); acc01 = MFMA(ah0, wl1, acc01); acc01 = MFMA(al0, wh1, acc01);
    acc10 = MFMA(ah1, wh0, acc10); acc10 = MFMA(ah1, wl0, acc10); acc10 = MFMA(al1, wh0, acc10);
    acc11 = MFMA(ah1, wh1, acc11); acc11 = MFMA(ah1, wl1, acc11); acc11 = MFMA(al1, wh1, acc11);
  }
  int gcol0 = rW + fr, gcol1 = rW + 16 + fr;
  float bz0 = bz[gcol0], bz1 = bz[gcol1];
#pragma unroll
  for (int i = 0; i < 4; i++) {
    size_t ro0 = ((size_t)b * N_ + rA + r0 + i) * (2 * C_);
    YZ[ro0 + gcol0] = acc00[i] + bz0;
    YZ[ro0 + gcol1] = acc01[i] + bz1;
    size_t ro1 = ((size_t)b * N_ + rA + 16 + r0 + i) * (2 * C_);
    YZ[ro1 + gcol0] = acc10[i] + bz0;
    YZ[ro1 + gcol1] = acc11[i] + bz1;
  }
}

// ---- combine: out[n][o] = max_k leaky(Y[idx[k]][o] + Z[n][o]); emit bf16 H/L ----
__global__ __launch_bounds__(384) void k_combine(const float* __restrict__ YZ,
                                                 const int* __restrict__ idx,
                                                 short* __restrict__ Hout,
                                                 short* __restrict__ Lout, int cofo) {
  __shared__ int sidx[4][K_];
  int n0 = blockIdx.x * 4, b = blockIdx.y, o = threadIdx.x;
  if (o < 4 * K_) {
    int qq = o / K_, r = o % K_;
    sidx[qq][r] = idx[((size_t)b * N_ + n0 + qq) * K_ + r];
  }
  __syncthreads();
  const float* baseYZ = YZ + (size_t)b * N_ * (2 * C_);
#pragma unroll
  for (int nn = 0; nn < 4; nn++) {
    int n = n0 + nn;
    float z = baseYZ[(size_t)n * (2 * C_) + C_ + o];
    float hmax = -INFINITY;
#pragma unroll
    for (int k = 0; k < K_; k++) {
      float y = baseYZ[(size_t)sidx[nn][k] * (2 * C_) + o];
      float s = y + z;
      s = s > 0.f ? s : SLOPE_ * s;
      hmax = fmaxf(hmax, s);
    }
    short hb = f2b(hmax);
    short lb = f2b(hmax - b2f(hb));
    size_t off = ((size_t)b * N_ + n) * (3 * C_) + cofo + o;
    Hout[off] = hb;
    Lout[off] = lb;
  }
}

// ---- final GEMM (split MFMA, K=1152) + leaky + max over rows + atomicMax ----
__global__ __launch_bounds__(256) void k_fingemm(const short* __restrict__ Hcat,
                                                 const short* __restrict__ Lcat,
                                                 const short* __restrict__ WpH,
                                                 const short* __restrict__ WpL,
                                                 const float* __restrict__ bz2,
                                                 unsigned* __restrict__ stage) {
  __shared__ float Sm[8][72];
  int bi = blockIdx.x, bj = blockIdx.y, b = blockIdx.z;
  int tid = threadIdx.x, lane = tid & 63, w = tid >> 6;
  int wr = w >> 1, wc = w & 1;
  int fr = lane & 15, fk = (lane >> 4) << 3;
  const short* Hb = Hcat + (size_t)b * N_ * (3 * C_);
  const short* Lb = Lcat + (size_t)b * N_ * (3 * C_);
  int rA = bi * 64 + wr * 32, rW = bj * 64 + wc * 32;

  floatx4 acc00 = {0.f, 0.f, 0.f, 0.f}, acc01 = {0.f, 0.f, 0.f, 0.f};
  floatx4 acc10 = {0.f, 0.f, 0.f, 0.f}, acc11 = {0.f, 0.f, 0.f, 0.f};

  for (int kc = 0; kc < 3 * C_; kc += 32) {
    short8 ah0 = *(const short8*)(Hb + (size_t)(rA + fr) * (3 * C_) + kc + fk);
    short8 ah1 = *(const short8*)(Hb + (size_t)(rA + 16 + fr) * (3 * C_) + kc + fk);
    short8 al0 = *(const short8*)(Lb + (size_t)(rA + fr) * (3 * C_) + kc + fk);
    short8 al1 = *(const short8*)(Lb + (size_t)(rA + 16 + fr) * (3 * C_) + kc + fk);
    short8 wh0 = *(const short8*)(WpH + (size_t)(rW + fr) * (3 * C_) + kc + fk);
    short8 wh1 = *(const short8*)(WpH + (size_t)(rW + 16 + fr) * (3 * C_) + kc + fk);
    short8 wl0 = *(const short8*)(WpL + (size_t)(rW + fr) * (3 * C_) + kc + fk);
    short8 wl1 = *(const short8*)(WpL + (size_t)(rW + 16 + fr) * (3 * C_) + kc + fk);
    acc00 = MFMA(ah0, wh0, acc00); acc00 = MFMA(ah0, wl0, acc00); acc00 = MFMA(al0, wh0, acc00);
    acc01 = MFMA(ah0, wh1, acc01); acc01 = MFMA(ah0, wl1, acc01); acc01 = MFMA(al0, wh1, acc01);
    acc10 = MFMA(ah1, wh0, acc10); acc10 = MFMA(ah1, wl0, acc10); acc10 = MFMA(al1, wh0, acc10);
    acc11 = MFMA(ah1, wh1, acc11); acc11 = MFMA(ah1, wl1, acc11); acc11 = MFMA(al1, wh1, acc11);
  }
  int gcol0 = rW + fr, gcol1 = rW + 16 + fr;
  float bz0 = bz2[gcol0], bz1 = bz2[gcol1];
  float cm0 = -INFINITY, cm1 = -INFINITY;
#pragma unroll
  for (int i = 0; i < 4; i++) {
    float y;
    y = acc00[i] + bz0; y = y > 0.f ? y : SLOPE_ * y; cm0 = fmaxf(cm0, y);
    y = acc10[i] + bz0; y = y > 0.f ? y : SLOPE_ * y; cm0 = fmaxf(cm0, y);
    y = acc01[i] + bz1; y = y > 0.f ? y : SLOPE_ * y; cm1 = fmaxf(cm1, y);
    y = acc11[i] + bz1; y = y > 0.f ? y : SLOPE_ * y; cm1 = fmaxf(cm1, y);
  }
  Sm[wr * 4 + (lane >> 4)][wc * 32 + fr] = cm0;
  Sm[wr * 4 + (lane >> 4)][wc * 32 + 16 + fr] = cm1;
  __syncthreads();
  if (tid < 64) {
    float mm = Sm[0][tid];
#pragma unroll
    for (int r = 1; r < 8; r++) mm = fmaxf(mm, Sm[r][tid]);
    atomicMax(stage + (size_t)b * C_ + bj * 64 + tid, fmap(mm));
  }
}

__global__ void k_init(unsigned* __restrict__ stage) {
  int t = blockIdx.x * 256 + threadIdx.x;
  if (t < B_ * C_) stage[t] = 0x007FFFFFu;  // fmap(-inf)
}

__global__ void k_unmap(const unsigned* __restrict__ stage, float* __restrict__ out) {
  int t = blockIdx.x * 256 + threadIdx.x;
  if (t < B_ * C_) out[t] = funmap(stage[t]);
}

// ---------------- host ----------------
extern "C" void kernel_launch(void* const* d_in, const int* in_sizes, int n_in,
                              void* d_out, int out_size, void* d_ws, size_t ws_size,
                              hipStream_t stream) {
  const float* x   = (const float*)d_in[0];
  const float* We[3] = {(const float*)d_in[2], (const float*)d_in[7], (const float*)d_in[12]};
  const float* g[3]  = {(const float*)d_in[3], (const float*)d_in[8], (const float*)d_in[13]};
  const float* bb[3] = {(const float*)d_in[4], (const float*)d_in[9], (const float*)d_in[14]};
  const float* m[3]  = {(const float*)d_in[5], (const float*)d_in[10], (const float*)d_in[15]};
  const float* v[3]  = {(const float*)d_in[6], (const float*)d_in[11], (const float*)d_in[16]};
  const float* Wp = (const float*)d_in[17];
  const float* gp = (const float*)d_in[18];
  const float* bp = (const float*)d_in[19];
  const float* mp = (const float*)d_in[20];
  const float* vp = (const float*)d_in[21];
  float* out = (float*)d_out;

  // workspace carve (all region boundaries 16B-aligned)
  float* Gm = (float*)d_ws;                              // B*N*N f32 (YZ aliases)
  float* YZ = Gm;
  float* sq = Gm + (size_t)B_ * N_ * N_;                 // B*N
  int* idx = (int*)(sq + (size_t)B_ * N_);               // B*N*K
  short* Hcat = (short*)(idx + (size_t)B_ * N_ * K_);    // B*N*3C bf16
  short* Lcat = Hcat + (size_t)B_ * N_ * 3 * C_;         // B*N*3C bf16
  short* H0   = Lcat + (size_t)B_ * N_ * 3 * C_;         // B*N*C bf16
  short* L0   = H0 + (size_t)B_ * N_ * C_;               // B*N*C bf16
  short* WbfH = L0 + (size_t)B_ * N_ * C_;               // 3 x 2C*C
  short* WbfL = WbfH + (size_t)3 * 2 * C_ * C_;          // 3 x 2C*C
  short* WpH  = WbfL + (size_t)3 * 2 * C_ * C_;          // C*3C
  short* WpL  = WpH + (size_t)C_ * 3 * C_;               // C*3C
  float* bz   = (float*)(WpL + (size_t)C_ * 3 * C_);     // 3 x 2C
  float* bz2  = bz + 3 * 2 * C_;                         // C
  unsigned* stage = (unsigned*)(bz2 + C_);               // B*C

  for (int l = 0; l < 3; l++)
    k_prepw<<<dim3((2 * C_ * C_ + 255) / 256), 256, 0, stream>>>(
        We[l], g[l], bb[l], m[l], v[l],
        WbfH + (size_t)l * 2 * C_ * C_, WbfL + (size_t)l * 2 * C_ * C_,
        bz + (size_t)l * 2 * C_);
  k_prepwp<<<dim3((3 * C_ * C_ + 255) / 256), 256, 0, stream>>>(Wp, gp, bp, mp, vp, WpH, WpL, bz2);
  k_transpose<<<dim3(N_ / 32, C_ / 32, B_), 256, 0, stream>>>(x, H0, L0);
  k_init<<<dim3((B_ * C_ + 255) / 256), 256, 0, stream>>>(stage);

  for (int l = 0; l < 3; l++) {
    const short* Hin = (l == 0) ? H0 : Hcat;
    const short* Lin = (l == 0) ? L0 : Lcat;
    int ldh  = (l == 0) ? C_ : 3 * C_;
    int coff = (l == 0) ? 0 : (l - 1) * C_;

    k_rowsq<<<dim3(B_ * N_ / 4), 256, 0, stream>>>(Hin, Lin, ldh, coff, sq);
    k_gram<<<dim3((N_ / 64) * (N_ / 64 + 1) / 2, 1, B_), 256, 0, stream>>>(
        Hin, Lin, ldh, coff, sq, Gm);
    k_topk<<<dim3(N_ / 4, B_), 256, 0, stream>>>(Gm, idx);
    // Gm fully consumed by topk; YZ aliases Gm (stream-ordered)
    k_yzgemm<<<dim3(N_ / 64, 2 * C_ / 64, B_), 256, 0, stream>>>(
        Hin, Lin, ldh, coff,
        WbfH + (size_t)l * 2 * C_ * C_, WbfL + (size_t)l * 2 * C_ * C_,
        bz + (size_t)l * 2 * C_, YZ);
    k_combine<<<dim3(N_ / 4, B_), 384, 0, stream>>>(YZ, idx, Hcat, Lcat, l * C_);
  }

  k_fingemm<<<dim3(N_ / 64, C_ / 64, B_), 256, 0, stream>>>(Hcat, Lcat, WpH, WpL, bz2, stage);
  k_unmap<<<dim3((B_ * C_ + 255) / 256), 256, 0, stream>>>(stage, out);
}